// Round 1
// baseline (1129.516 us; speedup 1.0000x reference)
//
#include <hip/hip_runtime.h>
#include <math.h>

#define NN 50000
#define EE 800000
#define HH 128
#define LL 3
#define GG 128

// ---------------------------------------------------------------- utilities
__global__ void zero_i32(int* p, int n){
  int i = blockIdx.x*blockDim.x + threadIdx.x;
  if (i < n) p[i] = 0;
}

// degree histogram over dst
__global__ void deg_kernel(const int* __restrict__ ei, int* __restrict__ deg){
  int e = blockIdx.x*blockDim.x + threadIdx.x;
  if (e < EE) atomicAdd(&deg[ei[EE + e]], 1);
}

// single-block exclusive scan: deg -> rowstart[0..n], cursor copy
// (deg may alias cursor: each element is read then written by the same thread)
__global__ void scan_kernel(const int* deg, int* rowstart, int* cursor, int n){
  __shared__ int wsum[16], woff[16];
  __shared__ int carry_s;
  const int tid = threadIdx.x, lane = tid & 63, wid = tid >> 6;
  if (tid == 0) carry_s = 0;
  __syncthreads();
  for (int base = 0; base < n; base += 1024){
    int i = base + tid;
    int v = (i < n) ? deg[i] : 0;
    int incl = v;
    #pragma unroll
    for (int off = 1; off < 64; off <<= 1){
      int t = __shfl_up(incl, off);
      if (lane >= off) incl += t;
    }
    if (lane == 63) wsum[wid] = incl;
    __syncthreads();
    if (tid < 16){
      int wv = wsum[tid];
      int winc = wv;
      #pragma unroll
      for (int off = 1; off < 16; off <<= 1){
        int t = __shfl_up(winc, off);
        if (tid >= off) winc += t;
      }
      woff[tid] = winc - wv;
    }
    __syncthreads();
    int c = carry_s;
    if (i < n){
      int excl = c + woff[wid] + incl - v;
      rowstart[i] = excl;
      cursor[i]   = excl;
    }
    __syncthreads();
    if (tid == 15) carry_s = c + woff[15] + wsum[15];
    __syncthreads();
  }
  if (tid == 0) rowstart[n] = carry_s;
}

__global__ void scatter_kernel(const int* __restrict__ ei, int* __restrict__ cursor,
                               int* __restrict__ csr){
  int e = blockIdx.x*blockDim.x + threadIdx.x;
  if (e < EE){
    int d = ei[EE + e];
    int w = atomicAdd(&cursor[d], 1);
    csr[w] = ei[e];
  }
}

// ------------------------------------------------------------- aggregation
// h[c][n] = x_in[c][n] + sum_{e: dst==n} x_in[c][src[e]]
// one wave per node; lane owns 2 features (float2).
// L0: x rows are z_table[0] or z_table[1] -> only neighbor COUNTS needed.
template<bool L0>
__global__ void agg_kernel(const int* __restrict__ rowstart, const int* __restrict__ csr,
                           const int* __restrict__ z, const float* __restrict__ ztab,
                           const float* __restrict__ xin,   // layers>=1: cat slice, stride 384
                           float* __restrict__ hout){
  const int lane = threadIdx.x & 63;
  const int n    = blockIdx.x*4 + (threadIdx.x >> 6);
  const int f2   = lane*2;
  const int e0 = rowstart[n], e1 = rowstart[n+1];
  float2 acc0, acc1;
  if (L0){
    float2 t0 = *(const float2*)&ztab[f2];
    float2 t1 = *(const float2*)&ztab[HH + f2];
    int c1 = 0, c2 = 0;
    for (int base = e0; base < e1; base += 64){
      if (base + lane < e1){
        int zs = z[csr[base + lane]];
        c1 += (zs == 1); c2 += (zs == 2);
      }
    }
    #pragma unroll
    for (int off = 1; off < 64; off <<= 1){
      c1 += __shfl_xor(c1, off);
      c2 += __shfl_xor(c2, off);
    }
    int zn  = z[n];
    int deg = e1 - e0;
    float w1a = (float)((zn == 1) + c1), w0a = (float)((zn != 1) + deg - c1);
    float w1b = (float)((zn == 2) + c2), w0b = (float)((zn != 2) + deg - c2);
    acc0.x = w1a*t1.x + w0a*t0.x;  acc0.y = w1a*t1.y + w0a*t0.y;
    acc1.x = w1b*t1.x + w0b*t0.x;  acc1.y = w1b*t1.y + w0b*t0.y;
  } else {
    const float* r0 = xin + (long)n*384 + f2;
    acc0 = *(const float2*)r0;
    acc1 = *(const float2*)(r0 + (long)NN*384);
    for (int base = e0; base < e1; base += 64){
      int m  = (e1 - base < 64) ? (e1 - base) : 64;
      int sl = (base + lane < e1) ? csr[base + lane] : 0;
      #pragma unroll 4
      for (int j = 0; j < m; ++j){
        int s = __shfl(sl, j);
        const float* p = xin + (long)s*384 + f2;
        float2 v0 = *(const float2*)p;
        float2 v1 = *(const float2*)(p + (long)NN*384);
        acc0.x += v0.x; acc0.y += v0.y;
        acc1.x += v1.x; acc1.y += v1.y;
      }
    }
  }
  float* o = hout + (long)n*HH + f2;
  *(float2*)o = acc0;
  *(float2*)(o + (long)NN*HH) = acc1;
}

// ------------------------------------------------------------------- GEMM
// C = act(A @ W + bias), optional fused LayerNorm epilogue.
// A: [M x K] row-major (lda), W: [K x 128] row-major, C: [M x 128] (ldc).
// 128x128 tile, 256 threads, 8x8 per-thread, K-chunks of 32 in LDS.
template<int K, bool DOLN>
__global__ __launch_bounds__(256, 4)
void gemm_kernel(const float* __restrict__ A, int lda,
                 const float* __restrict__ W, const float* __restrict__ bias,
                 const float* __restrict__ gamma, const float* __restrict__ beta,
                 float* __restrict__ C, int ldc, int M){
  __shared__ float AsT[32][132];   // A-chunk transposed, +4 pad
  __shared__ float Ws[32][128];
  const int tid = threadIdx.x;
  // wave-local 8x8 (tx,ty) layout -> all inner LDS reads are <=2-way conflicts
  const int tx = (tid & 7) | ((tid >> 4) & 8);    // bits {0,1,2, 7}
  const int ty = (tid >> 3) & 15;                 // bits {3,4,5, 6}
  const int rowBase = blockIdx.x * 128;

  float acc[8][8];
  #pragma unroll
  for (int i = 0; i < 8; i++)
    #pragma unroll
    for (int j = 0; j < 8; j++) acc[i][j] = 0.f;

  #pragma unroll 1
  for (int kc = 0; kc < K; kc += 32){
    #pragma unroll
    for (int p = 0; p < 4; p++){
      int lin = p*1024 + tid*4;
      int row = lin >> 5;
      int k   = lin & 31;
      int gr  = rowBase + row;
      float4 v = make_float4(0.f, 0.f, 0.f, 0.f);
      if (gr < M) v = *(const float4*)&A[(long)gr*lda + kc + k];
      AsT[k+0][row] = v.x; AsT[k+1][row] = v.y;
      AsT[k+2][row] = v.z; AsT[k+3][row] = v.w;
      int wk = lin >> 7, wc = lin & 127;
      float4 wv = *(const float4*)&W[(long)(kc + wk)*128 + wc];
      *(float4*)&Ws[wk][wc] = wv;
    }
    __syncthreads();
    #pragma unroll 8
    for (int kk = 0; kk < 32; kk++){
      float a[8], w[8];
      *(float4*)&a[0] = *(const float4*)&AsT[kk][ty*8];
      *(float4*)&a[4] = *(const float4*)&AsT[kk][ty*8 + 4];
      *(float4*)&w[0] = *(const float4*)&Ws[kk][tx*8];
      *(float4*)&w[4] = *(const float4*)&Ws[kk][tx*8 + 4];
      #pragma unroll
      for (int i = 0; i < 8; i++)
        #pragma unroll
        for (int j = 0; j < 8; j++)
          acc[i][j] = fmaf(a[i], w[j], acc[i][j]);
    }
    __syncthreads();
  }

  const int col0 = tx*8;
  float bb[8];
  #pragma unroll
  for (int j = 0; j < 8; j++) bb[j] = bias[col0 + j];
  #pragma unroll
  for (int i = 0; i < 8; i++)
    #pragma unroll
    for (int j = 0; j < 8; j++){
      float v = acc[i][j] + bb[j];
      acc[i][j] = v > 0.f ? v : 0.f;
    }

  if (DOLN){
    // cross-wave row stats via LDS (overlaid on AsT/Ws, dead after K-loop sync)
    float2* red   = (float2*)&AsT[0][0];   // [16][129] float2 (16512 B < 16896 B)
    float2* stats = (float2*)&Ws[0][0];    // [128] float2
    #pragma unroll
    for (int i = 0; i < 8; i++){
      float s = 0.f, q = 0.f;
      #pragma unroll
      for (int j = 0; j < 8; j++){ s += acc[i][j]; q += acc[i][j]*acc[i][j]; }
      red[tx*129 + ty*8 + i] = make_float2(s, q);
    }
    __syncthreads();
    if (tid < 128){
      float S = 0.f, Q = 0.f;
      #pragma unroll
      for (int t = 0; t < 16; t++){ float2 p = red[t*129 + tid]; S += p.x; Q += p.y; }
      float m   = S * (1.f/128.f);
      float var = Q * (1.f/128.f) - m*m;
      stats[tid] = make_float2(m, 1.f/sqrtf(var + 1e-5f));
    }
    __syncthreads();
    float gg[8], be[8];
    #pragma unroll
    for (int j = 0; j < 8; j++){ gg[j] = gamma[col0 + j]; be[j] = beta[col0 + j]; }
    #pragma unroll
    for (int i = 0; i < 8; i++){
      float2 st = stats[ty*8 + i];
      #pragma unroll
      for (int j = 0; j < 8; j++)
        acc[i][j] = (acc[i][j] - st.x)*st.y*gg[j] + be[j];
    }
  }

  #pragma unroll
  for (int i = 0; i < 8; i++){
    int gr = rowBase + ty*8 + i;
    if (gr < M){
      *(float4*)&C[(long)gr*ldc + col0]     = *(float4*)&acc[i][0];
      *(float4*)&C[(long)gr*ldc + col0 + 4] = *(float4*)&acc[i][4];
    }
  }
}

// ------------------------------------------------------ pooling + MLP head
// batch is sorted -> per-graph contiguous [s,e) found by binary search.
__global__ void pool_kernel(const float* __restrict__ y2, const int* __restrict__ batch,
                            const float* __restrict__ WA, const float* __restrict__ bA,
                            const float* __restrict__ WB, const float* __restrict__ bB,
                            float* __restrict__ out){
  const int g = blockIdx.x, tid = threadIdx.x;
  __shared__ int se[2];
  if (tid < 2){
    int target = g + tid;
    int lo = 0, hi = NN;
    while (lo < hi){ int mid = (lo + hi) >> 1; if (batch[mid] < target) lo = mid + 1; else hi = mid; }
    se[tid] = lo;
  }
  __syncthreads();
  const int s = se[0], e = se[1];
  float acc = 0.f;
  for (int n = s; n < e; n++)
    acc += y2[(long)n*HH + tid] + y2[(long)(NN + n)*HH + tid];
  float cnt = (float)(e - s); if (cnt < 1.f) cnt = 1.f;
  __shared__ float ms[HH];
  ms[tid] = acc / cnt;
  __syncthreads();
  float t = bA[tid];
  #pragma unroll 8
  for (int k = 0; k < HH; k++) t = fmaf(ms[k], WA[k*HH + tid], t);
  t = t > 0.f ? t : 0.f;
  float v = t * WB[tid];
  #pragma unroll
  for (int off = 32; off >= 1; off >>= 1) v += __shfl_down(v, off);
  __shared__ float r2[2];
  if ((tid & 63) == 0) r2[tid >> 6] = v;
  __syncthreads();
  if (tid == 0) out[g] = r2[0] + r2[1] + bB[0];
}

// ----------------------------------------------------------------- launch
extern "C" void kernel_launch(void* const* d_in, const int* in_sizes, int n_in,
                              void* d_out, int out_size, void* d_ws, size_t ws_size,
                              hipStream_t stream){
  const int*   z     = (const int*)  d_in[0];
  const int*   ei    = (const int*)  d_in[1];
  const int*   batch = (const int*)  d_in[2];
  const float* ztab  = (const float*)d_in[3];
  const float* W1s   = (const float*)d_in[4];
  const float* b1s   = (const float*)d_in[5];
  const float* W2s   = (const float*)d_in[6];
  const float* b2s   = (const float*)d_in[7];
  const float* lng   = (const float*)d_in[8];
  const float* lnb   = (const float*)d_in[9];
  const float* lin0W = (const float*)d_in[10];
  const float* lin0b = (const float*)d_in[11];
  const float* linAW = (const float*)d_in[12];
  const float* linAb = (const float*)d_in[13];
  const float* linBW = (const float*)d_in[14];
  const float* linBb = (const float*)d_in[15];
  float* out = (float*)d_out;

  char* ws = (char*)d_ws;
  size_t off = 0;
  auto alloc = [&](size_t bytes)->char*{
    char* p = ws + off;
    off = (off + bytes + 255) & ~(size_t)255;
    return p;
  };
  float* cat      = (float*)alloc((size_t)2*NN*384*sizeof(float)); // x1|x2|x3
  float* h        = (float*)alloc((size_t)2*NN*HH*sizeof(float));  // agg out / y2
  float* t        = (float*)alloc((size_t)2*NN*HH*sizeof(float));  // mid-MLP
  int*   rowstart = (int*)  alloc((size_t)(NN+1)*sizeof(int));
  int*   cursor   = (int*)  alloc((size_t)NN*sizeof(int));
  int*   csr      = (int*)  alloc((size_t)EE*sizeof(int));

  const int M = 2*NN;
  const int gemmGrid = (M + 127)/128;

  // CSR build (per call; ws is re-poisoned every launch)
  zero_i32<<<(NN + 255)/256, 256, 0, stream>>>(cursor, NN);
  deg_kernel<<<EE/256, 256, 0, stream>>>(ei, cursor);
  scan_kernel<<<1, 1024, 0, stream>>>(cursor, rowstart, cursor, NN);
  scatter_kernel<<<EE/256, 256, 0, stream>>>(ei, cursor, csr);

  for (int l = 0; l < LL; l++){
    if (l == 0)
      agg_kernel<true ><<<NN/4, 256, 0, stream>>>(rowstart, csr, z, ztab, nullptr, h);
    else
      agg_kernel<false><<<NN/4, 256, 0, stream>>>(rowstart, csr, z, ztab, cat + (l-1)*HH, h);
    gemm_kernel<128,false><<<gemmGrid, 256, 0, stream>>>(h, HH, W1s + l*HH*HH, b1s + l*HH,
                                                         nullptr, nullptr, t, HH, M);
    gemm_kernel<128,true ><<<gemmGrid, 256, 0, stream>>>(t, HH, W2s + l*HH*HH, b2s + l*HH,
                                                         lng + l*HH, lnb + l*HH,
                                                         cat + l*HH, LL*HH, M);
  }
  // lin0 over JK-concat, relu; sum over the 2 label channels happens in pool
  gemm_kernel<384,false><<<gemmGrid, 256, 0, stream>>>(cat, LL*HH, lin0W, lin0b,
                                                       nullptr, nullptr, h, HH, M);
  pool_kernel<<<GG, HH, 0, stream>>>(h, batch, linAW, linAb, linBW, linBb, out);
}

// Round 2
// 940.047 us; speedup vs baseline: 1.2016x; 1.2016x over previous
//
#include <hip/hip_runtime.h>
#include <math.h>

#define NN 50000
#define EE 800000
#define HH 128
#define LL 3
#define GG 128
#define MM (2*NN)

typedef unsigned int u32;
typedef unsigned short u16;
using s16x8 = __attribute__((ext_vector_type(8))) short;
using f32x4 = __attribute__((ext_vector_type(4))) float;

// ---- split-bf16 helpers: value stored as u32 = bf16_hi | (bf16_lo << 16) ----
__device__ __forceinline__ u16 f2bf(float f){
  u32 u = __float_as_uint(f);
  return (u16)((u + 0x7fffu + ((u >> 16) & 1u)) >> 16);   // RNE
}
__device__ __forceinline__ float bf2f(u16 h){ return __uint_as_float(((u32)h) << 16); }
__device__ __forceinline__ u32 splitpack(float v){
  u16 h = f2bf(v);
  float r = v - bf2f(h);          // exact (hi within 2^-8 of v)
  u16 l = f2bf(r);
  return (u32)h | ((u32)l << 16);
}
__device__ __forceinline__ float unpack2(u32 u){  // hi + lo
  return __uint_as_float(u << 16) + __uint_as_float(u & 0xffff0000u);
}

// ---------------------------------------------------------------- utilities
__global__ void zero_i32(int* p, int n){
  int i = blockIdx.x*blockDim.x + threadIdx.x;
  if (i < n) p[i] = 0;
}

__global__ void deg_kernel(const int* __restrict__ ei, int* __restrict__ deg){
  int e = blockIdx.x*blockDim.x + threadIdx.x;
  if (e < EE) atomicAdd(&deg[ei[EE + e]], 1);
}

__global__ void scan_kernel(const int* deg, int* rowstart, int* cursor, int n){
  __shared__ int wsum[16], woff[16];
  __shared__ int carry_s;
  const int tid = threadIdx.x, lane = tid & 63, wid = tid >> 6;
  if (tid == 0) carry_s = 0;
  __syncthreads();
  for (int base = 0; base < n; base += 1024){
    int i = base + tid;
    int v = (i < n) ? deg[i] : 0;
    int incl = v;
    #pragma unroll
    for (int off = 1; off < 64; off <<= 1){
      int t = __shfl_up(incl, off);
      if (lane >= off) incl += t;
    }
    if (lane == 63) wsum[wid] = incl;
    __syncthreads();
    if (tid < 16){
      int wv = wsum[tid];
      int winc = wv;
      #pragma unroll
      for (int off = 1; off < 16; off <<= 1){
        int t = __shfl_up(winc, off);
        if (tid >= off) winc += t;
      }
      woff[tid] = winc - wv;
    }
    __syncthreads();
    int c = carry_s;
    if (i < n){
      int excl = c + woff[wid] + incl - v;
      rowstart[i] = excl;
      cursor[i]   = excl;
    }
    __syncthreads();
    if (tid == 15) carry_s = c + woff[15] + wsum[15];
    __syncthreads();
  }
  if (tid == 0) rowstart[n] = carry_s;
}

__global__ void scatter_kernel(const int* __restrict__ ei, int* __restrict__ cursor,
                               int* __restrict__ csr){
  int e = blockIdx.x*blockDim.x + threadIdx.x;
  if (e < EE){
    int d = ei[EE + e];
    int w = atomicAdd(&cursor[d], 1);
    csr[w] = ei[e];
  }
}

// ---------------------------------------------------- weight transpose+split
// Wt layout (u16): W1[l]: hi @ l*32768 + c*128 + k, lo @ +16384   ([col][k])
//                  W2[l]: base 98304 + same
//                  lin0 : hi @ 196608 + c*384 + k, lo @ +49152
__global__ void prep_w(const float* __restrict__ W1s, const float* __restrict__ W2s,
                       const float* __restrict__ lin0W, u16* __restrict__ wt){
  int idx = blockIdx.x*256 + threadIdx.x;       // 0..147455
  int srcsel = idx / 49152;
  int r = idx - srcsel*49152;
  int k = r >> 7, c = r & 127;
  const float* src = srcsel==0 ? W1s : (srcsel==1 ? W2s : lin0W);
  float v = src[r];
  u16 h = f2bf(v);
  u16 l = f2bf(v - bf2f(h));
  if (srcsel < 2){
    int ly = k >> 7, kk = k & 127;
    size_t o = (size_t)srcsel*98304 + (size_t)ly*32768 + (size_t)c*128 + kk;
    wt[o] = h; wt[o + 16384] = l;
  } else {
    size_t o = 196608 + (size_t)c*384 + k;
    wt[o] = h; wt[o + 49152] = l;
  }
}

// ------------------------------------------------------------- aggregation
// h[c][n] = x[c][n] + sum_{e: dst==n} x[c][src[e]]; split-u32 in/out.
template<bool L0>
__global__ void agg_kernel(const int* __restrict__ rowstart, const int* __restrict__ csr,
                           const int* __restrict__ z, const float* __restrict__ ztab,
                           const u32* __restrict__ xin,   // stride 384, ch offset NN*384
                           u32* __restrict__ hout){       // [2][NN][128]
  const int lane = threadIdx.x & 63;
  const int n    = blockIdx.x*4 + (threadIdx.x >> 6);
  const int f2   = lane*2;
  const int e0 = rowstart[n], e1 = rowstart[n+1];
  float2 acc0, acc1;
  if (L0){
    float2 t0 = *(const float2*)&ztab[f2];
    float2 t1 = *(const float2*)&ztab[HH + f2];
    int c1 = 0, c2 = 0;
    for (int base = e0; base < e1; base += 64){
      if (base + lane < e1){
        int zs = z[csr[base + lane]];
        c1 += (zs == 1); c2 += (zs == 2);
      }
    }
    #pragma unroll
    for (int off = 1; off < 64; off <<= 1){
      c1 += __shfl_xor(c1, off);
      c2 += __shfl_xor(c2, off);
    }
    int zn  = z[n];
    int deg = e1 - e0;
    float w1a = (float)((zn == 1) + c1), w0a = (float)((zn != 1) + deg - c1);
    float w1b = (float)((zn == 2) + c2), w0b = (float)((zn != 2) + deg - c2);
    acc0.x = w1a*t1.x + w0a*t0.x;  acc0.y = w1a*t1.y + w0a*t0.y;
    acc1.x = w1b*t1.x + w0b*t0.x;  acc1.y = w1b*t1.y + w0b*t0.y;
  } else {
    const u32* r0 = xin + (size_t)n*384 + f2;
    uint2 s0 = *(const uint2*)r0;
    uint2 s1 = *(const uint2*)(r0 + (size_t)NN*384);
    acc0.x = unpack2(s0.x); acc0.y = unpack2(s0.y);
    acc1.x = unpack2(s1.x); acc1.y = unpack2(s1.y);
    for (int base = e0; base < e1; base += 64){
      int m  = (e1 - base < 64) ? (e1 - base) : 64;
      int sl = (base + lane < e1) ? csr[base + lane] : 0;
      #pragma unroll 4
      for (int j = 0; j < m; ++j){
        int s = __shfl(sl, j);
        const u32* p = xin + (size_t)s*384 + f2;
        uint2 v0 = *(const uint2*)p;
        uint2 v1 = *(const uint2*)(p + (size_t)NN*384);
        acc0.x += unpack2(v0.x); acc0.y += unpack2(v0.y);
        acc1.x += unpack2(v1.x); acc1.y += unpack2(v1.y);
      }
    }
  }
  uint2 o0 = make_uint2(splitpack(acc0.x), splitpack(acc0.y));
  uint2 o1 = make_uint2(splitpack(acc1.x), splitpack(acc1.y));
  *(uint2*)(hout + (size_t)n*HH + f2) = o0;
  *(uint2*)(hout + (size_t)(NN + n)*HH + f2) = o1;
}

// ------------------------------------------------------------------- GEMM
// C = act(A @ W + bias) [+ LayerNorm], A: split-u32 [M x K] (lda), W: pre-split
// transposed planes [128 x K] u16, C: split-u32 or f32 (ldc).
// Split-bf16 MFMA: A=Ah+Al, W=Wh+Wl; C ≈ AhWh + AhWl + AlWh (3 MFMAs).
// Block: 128 threads = 2 waves, tile 128 rows x 128 cols; wave = 64 rows.
// Per wave: rt=4 (16-row), ct=8 (16-col), mfma_f32_16x16x32_bf16.
template<int K, bool DOLN, bool OUTF32>
__global__ __launch_bounds__(128, 2)
void gemm_mfma(const u32* __restrict__ Asp, int lda,
               const u16* __restrict__ WtHi, const u16* __restrict__ WtLo,
               const float* __restrict__ bias,
               const float* __restrict__ gamma, const float* __restrict__ beta,
               u32* __restrict__ Csp, float* __restrict__ Cf, int ldc){
  // LDS (u16 units): A_hi[0,4096) A_lo[4096,8192) B_hi[8192,12288) B_lo[12288,16384)
  // frag-order layout: [g(4)][row/col(128)][8 bf16] -> contiguous 16B per lane
  __shared__ u16 lds[16384];
  const int tid  = threadIdx.x;
  const int lane = tid & 63, w = tid >> 6;
  const int r16  = lane & 15, g = lane >> 4;
  const int rowBase = blockIdx.x * 128;

  f32x4 acc[4][8];
  #pragma unroll
  for (int i = 0; i < 4; i++)
    #pragma unroll
    for (int j = 0; j < 8; j++) acc[i][j] = (f32x4){0.f,0.f,0.f,0.f};

  const int arow = rowBase + tid;
  const bool avalid = arow < MM;
  const u32* aptr = Asp + (size_t)arow * lda;
  const u16* whi  = WtHi + (size_t)tid * K;
  const u16* wlo  = WtLo + (size_t)tid * K;

  for (int kc = 0; kc < K; kc += 32){
    // ---- stage A (deinterleave hi/lo), thread tid owns row tid ----
    #pragma unroll
    for (int p = 0; p < 8; p++){
      uint4 av = make_uint4(0,0,0,0);
      if (avalid) av = *(const uint4*)(aptr + kc + p*4);
      u32 h01 = (av.x & 0xffffu) | (av.y << 16);
      u32 h23 = (av.z & 0xffffu) | (av.w << 16);
      u32 l01 = (av.x >> 16) | (av.y & 0xffff0000u);
      u32 l23 = (av.z >> 16) | (av.w & 0xffff0000u);
      int base = ((p>>1)*128 + tid)*8 + (p&1)*4;
      *(uint2*)&lds[base]        = make_uint2(h01, h23);
      *(uint2*)&lds[4096 + base] = make_uint2(l01, l23);
    }
    // ---- stage B (pure copy from pre-split Wt), thread tid owns col tid ----
    #pragma unroll
    for (int p = 0; p < 4; p++){
      *(uint4*)&lds[8192  + (p*128 + tid)*8] = *(const uint4*)(whi + kc + p*8);
      *(uint4*)&lds[12288 + (p*128 + tid)*8] = *(const uint4*)(wlo + kc + p*8);
    }
    __syncthreads();
    s16x8 ahi[4], alo[4];
    #pragma unroll
    for (int i = 0; i < 4; i++){
      int idx = (g*128 + w*64 + i*16 + r16)*8;
      ahi[i] = *(const s16x8*)&lds[idx];
      alo[i] = *(const s16x8*)&lds[4096 + idx];
    }
    #pragma unroll
    for (int j = 0; j < 8; j++){
      int bidx = (g*128 + j*16 + r16)*8;
      s16x8 bhi = *(const s16x8*)&lds[8192  + bidx];
      s16x8 blo = *(const s16x8*)&lds[12288 + bidx];
      #pragma unroll
      for (int i = 0; i < 4; i++){
        acc[i][j] = __builtin_amdgcn_mfma_f32_16x16x32_bf16(ahi[i], bhi, acc[i][j], 0, 0, 0);
        acc[i][j] = __builtin_amdgcn_mfma_f32_16x16x32_bf16(ahi[i], blo, acc[i][j], 0, 0, 0);
        acc[i][j] = __builtin_amdgcn_mfma_f32_16x16x32_bf16(alo[i], bhi, acc[i][j], 0, 0, 0);
      }
    }
    __syncthreads();
  }

  // ---- epilogue: bias + relu (+ LN) + store ----
  float bb[8];
  #pragma unroll
  for (int j = 0; j < 8; j++) bb[j] = bias[j*16 + r16];
  #pragma unroll
  for (int i = 0; i < 4; i++)
    #pragma unroll
    for (int j = 0; j < 8; j++)
      #pragma unroll
      for (int c = 0; c < 4; c++){
        float t = acc[i][j][c] + bb[j];
        acc[i][j][c] = t > 0.f ? t : 0.f;
      }

  if (DOLN){
    float gg_[8], be[8];
    #pragma unroll
    for (int j = 0; j < 8; j++){ gg_[j] = gamma[j*16 + r16]; be[j] = beta[j*16 + r16]; }
    float mn[4][4], rs[4][4];
    #pragma unroll
    for (int i = 0; i < 4; i++)
      #pragma unroll
      for (int c = 0; c < 4; c++){
        float ss = 0.f, qq = 0.f;
        #pragma unroll
        for (int j = 0; j < 8; j++){ float t = acc[i][j][c]; ss += t; qq += t*t; }
        // reduce across the 16 lanes (cols) of this g-group
        #pragma unroll
        for (int off = 1; off < 16; off <<= 1){
          ss += __shfl_xor(ss, off);
          qq += __shfl_xor(qq, off);
        }
        float m   = ss * (1.f/128.f);
        float var = qq * (1.f/128.f) - m*m;
        mn[i][c] = m;
        rs[i][c] = rsqrtf(var + 1e-5f);
      }
    #pragma unroll
    for (int i = 0; i < 4; i++)
      #pragma unroll
      for (int j = 0; j < 8; j++)
        #pragma unroll
        for (int c = 0; c < 4; c++)
          acc[i][j][c] = (acc[i][j][c] - mn[i][c]) * rs[i][c] * gg_[j] + be[j];
  }

  #pragma unroll
  for (int i = 0; i < 4; i++)
    #pragma unroll
    for (int c = 0; c < 4; c++){
      int grow = rowBase + w*64 + i*16 + g*4 + c;     // C/D: col=lane&15, row=(lane>>4)*4+reg
      if (grow < MM){
        #pragma unroll
        for (int j = 0; j < 8; j++){
          int col = j*16 + r16;
          if (OUTF32) Cf [(size_t)grow*ldc + col] = acc[i][j][c];
          else        Csp[(size_t)grow*ldc + col] = splitpack(acc[i][j][c]);
        }
      }
    }
}

// ------------------------------------------------------ pooling + MLP head
__global__ void pool_kernel(const float* __restrict__ y2, const int* __restrict__ batch,
                            const float* __restrict__ WA, const float* __restrict__ bA,
                            const float* __restrict__ WB, const float* __restrict__ bB,
                            float* __restrict__ out){
  const int g = blockIdx.x, tid = threadIdx.x;
  __shared__ int se[2];
  if (tid < 2){
    int target = g + tid;
    int lo = 0, hi = NN;
    while (lo < hi){ int mid = (lo + hi) >> 1; if (batch[mid] < target) lo = mid + 1; else hi = mid; }
    se[tid] = lo;
  }
  __syncthreads();
  const int s = se[0], e = se[1];
  float acc = 0.f;
  for (int n = s; n < e; n++)
    acc += y2[(size_t)n*HH + tid] + y2[(size_t)(NN + n)*HH + tid];
  float cnt = (float)(e - s); if (cnt < 1.f) cnt = 1.f;
  __shared__ float ms[HH];
  ms[tid] = acc / cnt;
  __syncthreads();
  float t = bA[tid];
  #pragma unroll 8
  for (int k = 0; k < HH; k++) t = fmaf(ms[k], WA[k*HH + tid], t);
  t = t > 0.f ? t : 0.f;
  float v = t * WB[tid];
  #pragma unroll
  for (int off = 32; off >= 1; off >>= 1) v += __shfl_down(v, off);
  __shared__ float r2[2];
  if ((tid & 63) == 0) r2[tid >> 6] = v;
  __syncthreads();
  if (tid == 0) out[g] = r2[0] + r2[1] + bB[0];
}

// ----------------------------------------------------------------- launch
extern "C" void kernel_launch(void* const* d_in, const int* in_sizes, int n_in,
                              void* d_out, int out_size, void* d_ws, size_t ws_size,
                              hipStream_t stream){
  const int*   z     = (const int*)  d_in[0];
  const int*   ei    = (const int*)  d_in[1];
  const int*   batch = (const int*)  d_in[2];
  const float* ztab  = (const float*)d_in[3];
  const float* W1s   = (const float*)d_in[4];
  const float* b1s   = (const float*)d_in[5];
  const float* W2s   = (const float*)d_in[6];
  const float* b2s   = (const float*)d_in[7];
  const float* lng   = (const float*)d_in[8];
  const float* lnb   = (const float*)d_in[9];
  const float* lin0W = (const float*)d_in[10];
  const float* lin0b = (const float*)d_in[11];
  const float* linAW = (const float*)d_in[12];
  const float* linAb = (const float*)d_in[13];
  const float* linBW = (const float*)d_in[14];
  const float* linBb = (const float*)d_in[15];
  float* out = (float*)d_out;

  char* ws = (char*)d_ws;
  size_t off = 0;
  auto alloc = [&](size_t bytes)->char*{
    char* p = ws + off;
    off = (off + bytes + 255) & ~(size_t)255;
    return p;
  };
  u32* cat_sp   = (u32*)alloc((size_t)2*NN*384*4);   // JK concat, split-u32
  u32* h_sp     = (u32*)alloc((size_t)MM*HH*4);      // agg out
  u32* t_sp     = (u32*)alloc((size_t)MM*HH*4);      // mid-MLP; aliased as f32 y
  float* y      = (float*)t_sp;
  u16* wt       = (u16*)alloc(294912*2);             // transposed split weights
  int* rowstart = (int*)alloc((size_t)(NN+1)*4);
  int* cursor   = (int*)alloc((size_t)NN*4);
  int* csr      = (int*)alloc((size_t)EE*4);

  const int gemmGrid = (MM + 127)/128;   // 782

  prep_w<<<576, 256, 0, stream>>>(W1s, W2s, lin0W, wt);

  zero_i32<<<(NN + 255)/256, 256, 0, stream>>>(cursor, NN);
  deg_kernel<<<EE/256, 256, 0, stream>>>(ei, cursor);
  scan_kernel<<<1, 1024, 0, stream>>>(cursor, rowstart, cursor, NN);
  scatter_kernel<<<EE/256, 256, 0, stream>>>(ei, cursor, csr);

  for (int l = 0; l < LL; l++){
    if (l == 0)
      agg_kernel<true ><<<NN/4, 256, 0, stream>>>(rowstart, csr, z, ztab, nullptr, h_sp);
    else
      agg_kernel<false><<<NN/4, 256, 0, stream>>>(rowstart, csr, z, ztab, cat_sp + (l-1)*HH, h_sp);
    gemm_mfma<128,false,false><<<gemmGrid, 128, 0, stream>>>(
        h_sp, HH, wt + l*32768, wt + l*32768 + 16384,
        b1s + l*HH, nullptr, nullptr, t_sp, nullptr, HH);
    gemm_mfma<128,true ,false><<<gemmGrid, 128, 0, stream>>>(
        t_sp, HH, wt + 98304 + l*32768, wt + 98304 + l*32768 + 16384,
        b2s + l*HH, lng + l*HH, lnb + l*HH, cat_sp + l*HH, nullptr, LL*HH);
  }
  gemm_mfma<384,false,true ><<<gemmGrid, 128, 0, stream>>>(
      cat_sp, LL*HH, wt + 196608, wt + 245760,
      lin0b, nullptr, nullptr, nullptr, y, HH);
  pool_kernel<<<GG, HH, 0, stream>>>(y, batch, linAW, linAb, linBW, linBb, out);
}

// Round 4
// 827.147 us; speedup vs baseline: 1.3656x; 1.1365x over previous
//
#include <hip/hip_runtime.h>
#include <math.h>

#define NN 50000
#define EE 800000
#define HH 128
#define LL 3
#define GG 128
#define MM (2*NN)
#define PB1 1024   // pool phase-1 blocks

typedef unsigned int u32;
typedef unsigned short u16;
using s16x8 = __attribute__((ext_vector_type(8))) short;
using f32x4 = __attribute__((ext_vector_type(4))) float;

// ---- split-bf16 helpers: value stored as u32 = bf16_hi | (bf16_lo << 16) ----
__device__ __forceinline__ u16 f2bf(float f){
  u32 u = __float_as_uint(f);
  return (u16)((u + 0x7fffu + ((u >> 16) & 1u)) >> 16);   // RNE
}
__device__ __forceinline__ float bf2f(u16 h){ return __uint_as_float(((u32)h) << 16); }
__device__ __forceinline__ u32 splitpack(float v){
  u16 h = f2bf(v);
  float r = v - bf2f(h);
  u16 l = f2bf(r);
  return (u32)h | ((u32)l << 16);
}
__device__ __forceinline__ float unpack2(u32 u){  // hi + lo
  return __uint_as_float(u << 16) + __uint_as_float(u & 0xffff0000u);
}

// ---------------------------------------------------------------- utilities
__global__ void zero_i32(int* p, int n){
  int i = blockIdx.x*blockDim.x + threadIdx.x;
  if (i < n) p[i] = 0;
}

__global__ void deg_kernel(const int* __restrict__ ei, int* __restrict__ deg){
  int e = blockIdx.x*blockDim.x + threadIdx.x;
  if (e < EE) atomicAdd(&deg[ei[EE + e]], 1);
}

__global__ void scan_kernel(const int* deg, int* rowstart, int* cursor, int n){
  __shared__ int wsum[16], woff[16];
  __shared__ int carry_s;
  const int tid = threadIdx.x, lane = tid & 63, wid = tid >> 6;
  if (tid == 0) carry_s = 0;
  __syncthreads();
  for (int base = 0; base < n; base += 1024){
    int i = base + tid;
    int v = (i < n) ? deg[i] : 0;
    int incl = v;
    #pragma unroll
    for (int off = 1; off < 64; off <<= 1){
      int t = __shfl_up(incl, off);
      if (lane >= off) incl += t;
    }
    if (lane == 63) wsum[wid] = incl;
    __syncthreads();
    if (tid < 16){
      int wv = wsum[tid];
      int winc = wv;
      #pragma unroll
      for (int off = 1; off < 16; off <<= 1){
        int t = __shfl_up(winc, off);
        if (tid >= off) winc += t;
      }
      woff[tid] = winc - wv;
    }
    __syncthreads();
    int c = carry_s;
    if (i < n){
      int excl = c + woff[wid] + incl - v;
      rowstart[i] = excl;
      cursor[i]   = excl;
    }
    __syncthreads();
    if (tid == 15) carry_s = c + woff[15] + wsum[15];
    __syncthreads();
  }
  if (tid == 0) rowstart[n] = carry_s;
}

__global__ void scatter_kernel(const int* __restrict__ ei, int* __restrict__ cursor,
                               int* __restrict__ csr){
  int e = blockIdx.x*blockDim.x + threadIdx.x;
  if (e < EE){
    int d = ei[EE + e];
    int w = atomicAdd(&cursor[d], 1);
    csr[w] = ei[e];
  }
}

// ---------------------------------------------------- weight transpose+split
__global__ void prep_w(const float* __restrict__ W1s, const float* __restrict__ W2s,
                       const float* __restrict__ lin0W, u16* __restrict__ wt){
  int idx = blockIdx.x*256 + threadIdx.x;       // 0..147455
  int srcsel = idx / 49152;
  int r = idx - srcsel*49152;
  int k = r >> 7, c = r & 127;
  const float* src = srcsel==0 ? W1s : (srcsel==1 ? W2s : lin0W);
  float v = src[r];
  u16 h = f2bf(v);
  u16 l = f2bf(v - bf2f(h));
  if (srcsel < 2){
    int ly = k >> 7, kk = k & 127;
    size_t o = (size_t)srcsel*98304 + (size_t)ly*32768 + (size_t)c*128 + kk;
    wt[o] = h; wt[o + 16384] = l;
  } else {
    size_t o = 196608 + (size_t)c*384 + k;
    wt[o] = h; wt[o + 49152] = l;
  }
}

// ------------------------------------------------------------- aggregation
// h[c][n] = x[c][n] + sum_{e: dst==n} x[c][src[e]]; split-u32 in/out.
// One wave per node. Non-L0: lane covers BOTH channels' gather in one 16B load:
//   ch = lane>>5, features f4=(lane&31)*4 .. +3  (32 lanes x 16B = full 512B row)
template<bool L0>
__global__ void agg_kernel(const int* __restrict__ rowstart, const int* __restrict__ csr,
                           const int* __restrict__ z, const float* __restrict__ ztab,
                           const u32* __restrict__ xin,   // stride 384, ch offset NN*384
                           u32* __restrict__ hout){       // [2][NN][128]
  const int lane = threadIdx.x & 63;
  const int n    = blockIdx.x*4 + (threadIdx.x >> 6);
  const int e0 = rowstart[n], e1 = rowstart[n+1];
  if (L0){
    const int f2 = lane*2;
    float2 t0 = *(const float2*)&ztab[f2];
    float2 t1 = *(const float2*)&ztab[HH + f2];
    int c1 = 0, c2 = 0;
    for (int base = e0; base < e1; base += 64){
      if (base + lane < e1){
        int zs = z[csr[base + lane]];
        c1 += (zs == 1); c2 += (zs == 2);
      }
    }
    #pragma unroll
    for (int off = 1; off < 64; off <<= 1){
      c1 += __shfl_xor(c1, off);
      c2 += __shfl_xor(c2, off);
    }
    int zn  = z[n];
    int deg = e1 - e0;
    float w1a = (float)((zn == 1) + c1), w0a = (float)((zn != 1) + deg - c1);
    float w1b = (float)((zn == 2) + c2), w0b = (float)((zn != 2) + deg - c2);
    float2 acc0, acc1;
    acc0.x = w1a*t1.x + w0a*t0.x;  acc0.y = w1a*t1.y + w0a*t0.y;
    acc1.x = w1b*t1.x + w0b*t0.x;  acc1.y = w1b*t1.y + w0b*t0.y;
    *(uint2*)(hout + (size_t)n*HH + f2) =
        make_uint2(splitpack(acc0.x), splitpack(acc0.y));
    *(uint2*)(hout + (size_t)(NN + n)*HH + f2) =
        make_uint2(splitpack(acc1.x), splitpack(acc1.y));
  } else {
    const int ch = lane >> 5;
    const int f4 = (lane & 31) * 4;
    const u32* base = xin + (size_t)ch*NN*384 + f4;
    uint4 sv = *(const uint4*)(base + (size_t)n*384);
    float4 acc;
    acc.x = unpack2(sv.x); acc.y = unpack2(sv.y);
    acc.z = unpack2(sv.z); acc.w = unpack2(sv.w);
    for (int b = e0; b < e1; b += 64){
      int m  = (e1 - b < 64) ? (e1 - b) : 64;
      int sl = (b + lane < e1) ? csr[b + lane] : 0;
      #pragma unroll 4
      for (int j = 0; j < m; ++j){
        int s = __shfl(sl, j);
        uint4 v = *(const uint4*)(base + (size_t)s*384);
        acc.x += unpack2(v.x); acc.y += unpack2(v.y);
        acc.z += unpack2(v.z); acc.w += unpack2(v.w);
      }
    }
    uint4 o;
    o.x = splitpack(acc.x); o.y = splitpack(acc.y);
    o.z = splitpack(acc.z); o.w = splitpack(acc.w);
    *(uint4*)(hout + (size_t)ch*NN*HH + (size_t)n*HH + f4) = o;
  }
}

// ------------------------------------------------------------------- GEMM
template<int K, bool DOLN, bool OUTF32>
__global__ __launch_bounds__(128, 2)
void gemm_mfma(const u32* __restrict__ Asp, int lda,
               const u16* __restrict__ WtHi, const u16* __restrict__ WtLo,
               const float* __restrict__ bias,
               const float* __restrict__ gamma, const float* __restrict__ beta,
               u32* __restrict__ Csp, float* __restrict__ Cf, int ldc){
  __shared__ u16 lds[16384];
  const int tid  = threadIdx.x;
  const int lane = tid & 63, w = tid >> 6;
  const int r16  = lane & 15, g = lane >> 4;
  const int rowBase = blockIdx.x * 128;

  f32x4 acc[4][8];
  #pragma unroll
  for (int i = 0; i < 4; i++)
    #pragma unroll
    for (int j = 0; j < 8; j++) acc[i][j] = (f32x4){0.f,0.f,0.f,0.f};

  const int arow = rowBase + tid;
  const bool avalid = arow < MM;
  const u32* aptr = Asp + (size_t)arow * lda;
  const u16* whi  = WtHi + (size_t)tid * K;
  const u16* wlo  = WtLo + (size_t)tid * K;

  for (int kc = 0; kc < K; kc += 32){
    #pragma unroll
    for (int p = 0; p < 8; p++){
      uint4 av = make_uint4(0,0,0,0);
      if (avalid) av = *(const uint4*)(aptr + kc + p*4);
      u32 h01 = (av.x & 0xffffu) | (av.y << 16);
      u32 h23 = (av.z & 0xffffu) | (av.w << 16);
      u32 l01 = (av.x >> 16) | (av.y & 0xffff0000u);
      u32 l23 = (av.z >> 16) | (av.w & 0xffff0000u);
      int base = ((p>>1)*128 + tid)*8 + (p&1)*4;
      *(uint2*)&lds[base]        = make_uint2(h01, h23);
      *(uint2*)&lds[4096 + base] = make_uint2(l01, l23);
    }
    #pragma unroll
    for (int p = 0; p < 4; p++){
      *(uint4*)&lds[8192  + (p*128 + tid)*8] = *(const uint4*)(whi + kc + p*8);
      *(uint4*)&lds[12288 + (p*128 + tid)*8] = *(const uint4*)(wlo + kc + p*8);
    }
    __syncthreads();
    s16x8 ahi[4], alo[4];
    #pragma unroll
    for (int i = 0; i < 4; i++){
      int idx = (g*128 + w*64 + i*16 + r16)*8;
      ahi[i] = *(const s16x8*)&lds[idx];
      alo[i] = *(const s16x8*)&lds[4096 + idx];
    }
    #pragma unroll
    for (int j = 0; j < 8; j++){
      int bidx = (g*128 + j*16 + r16)*8;
      s16x8 bhi = *(const s16x8*)&lds[8192  + bidx];
      s16x8 blo = *(const s16x8*)&lds[12288 + bidx];
      #pragma unroll
      for (int i = 0; i < 4; i++){
        acc[i][j] = __builtin_amdgcn_mfma_f32_16x16x32_bf16(ahi[i], bhi, acc[i][j], 0, 0, 0);
        acc[i][j] = __builtin_amdgcn_mfma_f32_16x16x32_bf16(ahi[i], blo, acc[i][j], 0, 0, 0);
        acc[i][j] = __builtin_amdgcn_mfma_f32_16x16x32_bf16(alo[i], bhi, acc[i][j], 0, 0, 0);
      }
    }
    __syncthreads();
  }

  float bb[8];
  #pragma unroll
  for (int j = 0; j < 8; j++) bb[j] = bias[j*16 + r16];
  #pragma unroll
  for (int i = 0; i < 4; i++)
    #pragma unroll
    for (int j = 0; j < 8; j++)
      #pragma unroll
      for (int c = 0; c < 4; c++){
        float t = acc[i][j][c] + bb[j];
        acc[i][j][c] = t > 0.f ? t : 0.f;
      }

  if (DOLN){
    float gg_[8], be[8];
    #pragma unroll
    for (int j = 0; j < 8; j++){ gg_[j] = gamma[j*16 + r16]; be[j] = beta[j*16 + r16]; }
    float mn[4][4], rs[4][4];
    #pragma unroll
    for (int i = 0; i < 4; i++)
      #pragma unroll
      for (int c = 0; c < 4; c++){
        float ss = 0.f, qq = 0.f;
        #pragma unroll
        for (int j = 0; j < 8; j++){ float t = acc[i][j][c]; ss += t; qq += t*t; }
        #pragma unroll
        for (int off = 1; off < 16; off <<= 1){
          ss += __shfl_xor(ss, off);
          qq += __shfl_xor(qq, off);
        }
        float m   = ss * (1.f/128.f);
        float var = qq * (1.f/128.f) - m*m;
        mn[i][c] = m;
        rs[i][c] = rsqrtf(var + 1e-5f);
      }
    #pragma unroll
    for (int i = 0; i < 4; i++)
      #pragma unroll
      for (int j = 0; j < 8; j++)
        #pragma unroll
        for (int c = 0; c < 4; c++)
          acc[i][j][c] = (acc[i][j][c] - mn[i][c]) * rs[i][c] * gg_[j] + be[j];
  }

  #pragma unroll
  for (int i = 0; i < 4; i++)
    #pragma unroll
    for (int c = 0; c < 4; c++){
      int grow = rowBase + w*64 + i*16 + g*4 + c;
      if (grow < MM){
        #pragma unroll
        for (int j = 0; j < 8; j++){
          int col = j*16 + r16;
          if (OUTF32) Cf [(size_t)grow*ldc + col] = acc[i][j][c];
          else        Csp[(size_t)grow*ldc + col] = splitpack(acc[i][j][c]);
        }
      }
    }
}

// ------------------------------------------------------ pooling, 2 phases
// Phase 1: node-parallel partial sums. 1024 blocks x 128 threads; block owns a
// contiguous node slice; thread = feature; flush on graph change (batch sorted).
__global__ void pool1_kernel(const float* __restrict__ y2, const int* __restrict__ batch,
                             float* __restrict__ sums){
  const int npb = (NN + PB1 - 1)/PB1;   // 49
  int n0 = blockIdx.x * npb;
  if (n0 >= NN) return;
  int n1 = n0 + npb; if (n1 > NN) n1 = NN;
  const int f = threadIdx.x;
  float acc = 0.f;
  int g = batch[n0];
  for (int n = n0; n < n1; n++){
    int bg = batch[n];
    if (bg != g){
      atomicAdd(&sums[(size_t)g*HH + f], acc);
      acc = 0.f; g = bg;
    }
    acc += y2[(size_t)n*HH + f] + y2[(size_t)(NN + n)*HH + f];
  }
  atomicAdd(&sums[(size_t)g*HH + f], acc);
}

// Phase 2: per-graph mean + linA + relu + linB.
__global__ void pool2_kernel(const float* __restrict__ sums, const int* __restrict__ batch,
                             const float* __restrict__ WA, const float* __restrict__ bA,
                             const float* __restrict__ WB, const float* __restrict__ bB,
                             float* __restrict__ out){
  const int g = blockIdx.x, tid = threadIdx.x;
  __shared__ int se[2];
  if (tid < 2){
    int target = g + tid;
    int lo = 0, hi = NN;
    while (lo < hi){ int mid = (lo + hi) >> 1; if (batch[mid] < target) lo = mid + 1; else hi = mid; }
    se[tid] = lo;
  }
  __syncthreads();
  float cnt = (float)(se[1] - se[0]); if (cnt < 1.f) cnt = 1.f;
  __shared__ float ms[HH];
  ms[tid] = sums[(size_t)g*HH + tid] / cnt;
  __syncthreads();
  float t = bA[tid];
  #pragma unroll 8
  for (int k = 0; k < HH; k++) t = fmaf(ms[k], WA[k*HH + tid], t);
  t = t > 0.f ? t : 0.f;
  float v = t * WB[tid];
  #pragma unroll
  for (int off = 32; off >= 1; off >>= 1) v += __shfl_down(v, off);
  __shared__ float r2[2];
  if ((tid & 63) == 0) r2[tid >> 6] = v;
  __syncthreads();
  if (tid == 0) out[g] = r2[0] + r2[1] + bB[0];
}

// ----------------------------------------------------------------- launch
extern "C" void kernel_launch(void* const* d_in, const int* in_sizes, int n_in,
                              void* d_out, int out_size, void* d_ws, size_t ws_size,
                              hipStream_t stream){
  const int*   z     = (const int*)  d_in[0];
  const int*   ei    = (const int*)  d_in[1];
  const int*   batch = (const int*)  d_in[2];
  const float* ztab  = (const float*)d_in[3];
  const float* W1s   = (const float*)d_in[4];
  const float* b1s   = (const float*)d_in[5];
  const float* W2s   = (const float*)d_in[6];
  const float* b2s   = (const float*)d_in[7];
  const float* lng   = (const float*)d_in[8];
  const float* lnb   = (const float*)d_in[9];
  const float* lin0W = (const float*)d_in[10];
  const float* lin0b = (const float*)d_in[11];
  const float* linAW = (const float*)d_in[12];
  const float* linAb = (const float*)d_in[13];
  const float* linBW = (const float*)d_in[14];
  const float* linBb = (const float*)d_in[15];
  float* out = (float*)d_out;

  char* ws = (char*)d_ws;
  size_t off = 0;
  auto alloc = [&](size_t bytes)->char*{
    char* p = ws + off;
    off = (off + bytes + 255) & ~(size_t)255;
    return p;
  };
  u32* cat_sp   = (u32*)alloc((size_t)2*NN*384*4);   // JK concat, split-u32
  u32* h_sp     = (u32*)alloc((size_t)MM*HH*4);      // agg out
  u32* t_sp     = (u32*)alloc((size_t)MM*HH*4);      // mid-MLP; aliased as f32 y
  float* y      = (float*)t_sp;
  u16* wt       = (u16*)alloc(294912*2);             // transposed split weights
  float* sums   = (float*)alloc((size_t)GG*HH*4);    // pool partial sums
  int* rowstart = (int*)alloc((size_t)(NN+1)*4);
  int* cursor   = (int*)alloc((size_t)NN*4);
  int* csr      = (int*)alloc((size_t)EE*4);

  const int gemmGrid = (MM + 127)/128;   // 782

  prep_w<<<576, 256, 0, stream>>>(W1s, W2s, lin0W, wt);

  zero_i32<<<(NN + 255)/256, 256, 0, stream>>>(cursor, NN);
  zero_i32<<<(GG*HH)/256, 256, 0, stream>>>((int*)sums, GG*HH);
  deg_kernel<<<EE/256, 256, 0, stream>>>(ei, cursor);
  scan_kernel<<<1, 1024, 0, stream>>>(cursor, rowstart, cursor, NN);
  scatter_kernel<<<EE/256, 256, 0, stream>>>(ei, cursor, csr);

  for (int l = 0; l < LL; l++){
    if (l == 0)
      agg_kernel<true ><<<NN/4, 256, 0, stream>>>(rowstart, csr, z, ztab, nullptr, h_sp);
    else
      agg_kernel<false><<<NN/4, 256, 0, stream>>>(rowstart, csr, z, ztab, cat_sp + (l-1)*HH, h_sp);
    gemm_mfma<128,false,false><<<gemmGrid, 128, 0, stream>>>(
        h_sp, HH, wt + l*32768, wt + l*32768 + 16384,
        b1s + l*HH, nullptr, nullptr, t_sp, nullptr, HH);
    gemm_mfma<128,true ,false><<<gemmGrid, 128, 0, stream>>>(
        t_sp, HH, wt + 98304 + l*32768, wt + 98304 + l*32768 + 16384,
        b2s + l*HH, lng + l*HH, lnb + l*HH, cat_sp + l*HH, nullptr, LL*HH);
  }
  gemm_mfma<384,false,true ><<<gemmGrid, 128, 0, stream>>>(
      cat_sp, LL*HH, wt + 196608, wt + 245760,
      lin0b, nullptr, nullptr, nullptr, y, HH);
  pool1_kernel<<<PB1, HH, 0, stream>>>(y, batch, sums);
  pool2_kernel<<<GG, HH, 0, stream>>>(sums, batch, linAW, linAb, linBW, linBb, out);
}

// Round 8
// 782.975 us; speedup vs baseline: 1.4426x; 1.0564x over previous
//
#include <hip/hip_runtime.h>
#include <math.h>

#define NN 50000
#define EE 800000
#define HH 128
#define LL 3
#define GG 128
#define MM (2*NN)
#define PB1 1024   // pool phase-1 blocks

typedef unsigned int u32;
typedef unsigned short u16;
using s16x8 = __attribute__((ext_vector_type(8))) short;
using f32x4 = __attribute__((ext_vector_type(4))) float;

// ---- split-bf16 helpers: value stored as u32 = bf16_hi | (bf16_lo << 16) ----
__device__ __forceinline__ u16 f2bf(float f){
  u32 u = __float_as_uint(f);
  return (u16)((u + 0x7fffu + ((u >> 16) & 1u)) >> 16);   // RNE
}
__device__ __forceinline__ float bf2f(u16 h){ return __uint_as_float(((u32)h) << 16); }
__device__ __forceinline__ u32 splitpack(float v){
  u16 h = f2bf(v);
  float r = v - bf2f(h);
  u16 l = f2bf(r);
  return (u32)h | ((u32)l << 16);
}
__device__ __forceinline__ float unpack2(u32 u){  // hi + lo
  return __uint_as_float(u << 16) + __uint_as_float(u & 0xffff0000u);
}

// ---------------------------------------------------------------- utilities
__global__ void zero_i32(int* p, int n){
  int i = blockIdx.x*blockDim.x + threadIdx.x;
  if (i < n) p[i] = 0;
}

__global__ void deg_kernel(const int* __restrict__ ei, int* __restrict__ deg){
  int e = blockIdx.x*blockDim.x + threadIdx.x;
  if (e < EE) atomicAdd(&deg[ei[EE + e]], 1);
}

__global__ void scan_kernel(const int* deg, int* rowstart, int* cursor, int n){
  __shared__ int wsum[16], woff[16];
  __shared__ int carry_s;
  const int tid = threadIdx.x, lane = tid & 63, wid = tid >> 6;
  if (tid == 0) carry_s = 0;
  __syncthreads();
  for (int base = 0; base < n; base += 1024){
    int i = base + tid;
    int v = (i < n) ? deg[i] : 0;
    int incl = v;
    #pragma unroll
    for (int off = 1; off < 64; off <<= 1){
      int t = __shfl_up(incl, off);
      if (lane >= off) incl += t;
    }
    if (lane == 63) wsum[wid] = incl;
    __syncthreads();
    if (tid < 16){
      int wv = wsum[tid];
      int winc = wv;
      #pragma unroll
      for (int off = 1; off < 16; off <<= 1){
        int t = __shfl_up(winc, off);
        if (tid >= off) winc += t;
      }
      woff[tid] = winc - wv;
    }
    __syncthreads();
    int c = carry_s;
    if (i < n){
      int excl = c + woff[wid] + incl - v;
      rowstart[i] = excl;
      cursor[i]   = excl;
    }
    __syncthreads();
    if (tid == 15) carry_s = c + woff[15] + wsum[15];
    __syncthreads();
  }
  if (tid == 0) rowstart[n] = carry_s;
}

__global__ void scatter_kernel(const int* __restrict__ ei, int* __restrict__ cursor,
                               int* __restrict__ csr){
  int e = blockIdx.x*blockDim.x + threadIdx.x;
  if (e < EE){
    int d = ei[EE + e];
    int w = atomicAdd(&cursor[d], 1);
    csr[w] = ei[e];
  }
}

// ---------------------------------------------------- weight transpose+split
__global__ void prep_w(const float* __restrict__ W1s, const float* __restrict__ W2s,
                       const float* __restrict__ lin0W, u16* __restrict__ wt){
  int idx = blockIdx.x*256 + threadIdx.x;       // 0..147455
  int srcsel = idx / 49152;
  int r = idx - srcsel*49152;
  int k = r >> 7, c = r & 127;
  const float* src = srcsel==0 ? W1s : (srcsel==1 ? W2s : lin0W);
  float v = src[r];
  u16 h = f2bf(v);
  u16 l = f2bf(v - bf2f(h));
  if (srcsel < 2){
    int ly = k >> 7, kk = k & 127;
    size_t o = (size_t)srcsel*98304 + (size_t)ly*32768 + (size_t)c*128 + kk;
    wt[o] = h; wt[o + 16384] = l;
  } else {
    size_t o = 196608 + (size_t)c*384 + k;
    wt[o] = h; wt[o + 49152] = l;
  }
}

// ------------------------------------------------------------- aggregation
// h[c][n] = x[c][n] + sum_{e: dst==n} x[c][src[e]]; split-u32 in/out.
// Non-L0: input is compact xc layer slice [NN][256] (ch0|ch1 contiguous, 1KB).
// One wave per node: lane reads uint4 at node_row + lane*16B -> full row/edge.
template<bool L0>
__global__ void agg_kernel(const int* __restrict__ rowstart, const int* __restrict__ csr,
                           const int* __restrict__ z, const float* __restrict__ ztab,
                           const u32* __restrict__ xin,   // xc layer base [NN][256]
                           u32* __restrict__ hout){       // [2][NN][128]
  const int lane = threadIdx.x & 63;
  const int n    = blockIdx.x*4 + (threadIdx.x >> 6);
  const int e0 = rowstart[n], e1 = rowstart[n+1];
  if (L0){
    const int f2 = lane*2;
    float2 t0 = *(const float2*)&ztab[f2];
    float2 t1 = *(const float2*)&ztab[HH + f2];
    int c1 = 0, c2 = 0;
    for (int base = e0; base < e1; base += 64){
      if (base + lane < e1){
        int zs = z[csr[base + lane]];
        c1 += (zs == 1); c2 += (zs == 2);
      }
    }
    #pragma unroll
    for (int off = 1; off < 64; off <<= 1){
      c1 += __shfl_xor(c1, off);
      c2 += __shfl_xor(c2, off);
    }
    int zn  = z[n];
    int deg = e1 - e0;
    float w1a = (float)((zn == 1) + c1), w0a = (float)((zn != 1) + deg - c1);
    float w1b = (float)((zn == 2) + c2), w0b = (float)((zn != 2) + deg - c2);
    float2 acc0, acc1;
    acc0.x = w1a*t1.x + w0a*t0.x;  acc0.y = w1a*t1.y + w0a*t0.y;
    acc1.x = w1b*t1.x + w0b*t0.x;  acc1.y = w1b*t1.y + w0b*t0.y;
    *(uint2*)(hout + (size_t)n*HH + f2) =
        make_uint2(splitpack(acc0.x), splitpack(acc0.y));
    *(uint2*)(hout + (size_t)(NN + n)*HH + f2) =
        make_uint2(splitpack(acc1.x), splitpack(acc1.y));
  } else {
    const u32* base = xin + lane*4;          // lane*4 = ch*128 + (lane&31)*4
    uint4 sv = *(const uint4*)(base + (size_t)n*256);
    float4 acc;
    acc.x = unpack2(sv.x); acc.y = unpack2(sv.y);
    acc.z = unpack2(sv.z); acc.w = unpack2(sv.w);
    for (int b = e0; b < e1; b += 64){
      int m  = (e1 - b < 64) ? (e1 - b) : 64;
      int sl = (b + lane < e1) ? csr[b + lane] : 0;
      #pragma unroll 4
      for (int j = 0; j < m; ++j){
        int s = __shfl(sl, j);
        uint4 v = *(const uint4*)(base + (size_t)s*256);
        acc.x += unpack2(v.x); acc.y += unpack2(v.y);
        acc.z += unpack2(v.z); acc.w += unpack2(v.w);
      }
    }
    uint4 o;
    o.x = splitpack(acc.x); o.y = splitpack(acc.y);
    o.z = splitpack(acc.z); o.w = splitpack(acc.w);
    const int ch = lane >> 5, f = (lane & 31)*4;
    *(uint4*)(hout + ((size_t)ch*NN + n)*HH + f) = o;
  }
}

// ------------------------------------------------------------------- GEMM
// Split-bf16 MFMA GEMM, 128x128 tile, 256 threads = 4 waves (wave = 32 rows).
// MODE 0: A=[2NN][128] split-u32, epilogue relu -> Cu[2NN][128] split-u32
// MODE 1: A=[2NN][128],            epilogue relu+LN -> xc[n][256] compact split-u32
// MODE 2: A=xc triple [3][NN][256] (K=384), epilogue relu -> Cf[2NN][128] f32
template<int K, int MODE>
__global__ __launch_bounds__(256, 4)
void gemm_mfma(const u32* __restrict__ Asp,
               const u16* __restrict__ WtHi, const u16* __restrict__ WtLo,
               const float* __restrict__ bias,
               const float* __restrict__ gamma, const float* __restrict__ beta,
               u32* __restrict__ Cu, float* __restrict__ Cf){
  // LDS (u16): A_hi[0,4096) A_lo[4096,8192) B_hi[8192,12288) B_lo[12288,16384)
  // frag layout: [g(4)][row/col(128)][8 bf16]
  __shared__ u16 lds[16384];
  const int tid  = threadIdx.x;
  const int lane = tid & 63, w = tid >> 6;
  const int r16  = lane & 15, g = lane >> 4;
  const int rowBase = blockIdx.x * 128;

  f32x4 acc[2][8];
  #pragma unroll
  for (int i = 0; i < 2; i++)
    #pragma unroll
    for (int j = 0; j < 8; j++) acc[i][j] = (f32x4){0.f,0.f,0.f,0.f};

  const int sr = tid & 127;       // staging row (A) / col (B)
  const int kq = tid >> 7;        // k-half within 32-chunk
  const int arow = rowBase + sr;
  const bool avalid = arow < MM;
  const int ach = arow >= NN ? 1 : 0;
  const int an  = arow - ach*NN;

  const u16* whi = WtHi + (size_t)sr*K + kq*16;
  const u16* wlo = WtLo + (size_t)sr*K + kq*16;

  for (int kc = 0; kc < K; kc += 32){
    const int k0 = kc + kq*16;
    const u32* ap;
    if (MODE == 2)
      ap = Asp + ((size_t)(k0 >> 7))*NN*256 + (size_t)an*256 + ach*128 + (k0 & 127);
    else
      ap = Asp + (size_t)arow*128 + k0;
    #pragma unroll
    for (int q = 0; q < 4; q++){
      uint4 av = make_uint4(0,0,0,0);
      if (avalid) av = *(const uint4*)(ap + q*4);
      u32 h01 = (av.x & 0xffffu) | (av.y << 16);
      u32 h23 = (av.z & 0xffffu) | (av.w << 16);
      u32 l01 = (av.x >> 16) | (av.y & 0xffff0000u);
      u32 l23 = (av.z >> 16) | (av.w & 0xffff0000u);
      int k = kq*16 + q*4;                       // 0..31 in chunk
      int base = ((k >> 3)*128 + sr)*8 + (k & 7);
      *(uint2*)&lds[base]        = make_uint2(h01, h23);
      *(uint2*)&lds[4096 + base] = make_uint2(l01, l23);
    }
    #pragma unroll
    for (int hg = 0; hg < 2; hg++){
      int gsel = kq*2 + hg;
      *(uint4*)&lds[8192  + (gsel*128 + sr)*8] = *(const uint4*)(whi + kc + hg*8);
      *(uint4*)&lds[12288 + (gsel*128 + sr)*8] = *(const uint4*)(wlo + kc + hg*8);
    }
    __syncthreads();
    s16x8 ahi[2], alo[2];
    #pragma unroll
    for (int i = 0; i < 2; i++){
      int idx = (g*128 + w*32 + i*16 + r16)*8;
      ahi[i] = *(const s16x8*)&lds[idx];
      alo[i] = *(const s16x8*)&lds[4096 + idx];
    }
    #pragma unroll
    for (int j = 0; j < 8; j++){
      int bidx = (g*128 + j*16 + r16)*8;
      s16x8 bhi = *(const s16x8*)&lds[8192  + bidx];
      s16x8 blo = *(const s16x8*)&lds[12288 + bidx];
      #pragma unroll
      for (int i = 0; i < 2; i++){
        acc[i][j] = __builtin_amdgcn_mfma_f32_16x16x32_bf16(ahi[i], bhi, acc[i][j], 0, 0, 0);
        acc[i][j] = __builtin_amdgcn_mfma_f32_16x16x32_bf16(ahi[i], blo, acc[i][j], 0, 0, 0);
        acc[i][j] = __builtin_amdgcn_mfma_f32_16x16x32_bf16(alo[i], bhi, acc[i][j], 0, 0, 0);
      }
    }
    __syncthreads();
  }

  // ---- epilogue: bias + relu (+ LN) + store ----
  float bb[8];
  #pragma unroll
  for (int j = 0; j < 8; j++) bb[j] = bias[j*16 + r16];
  #pragma unroll
  for (int i = 0; i < 2; i++)
    #pragma unroll
    for (int j = 0; j < 8; j++)
      #pragma unroll
      for (int c = 0; c < 4; c++){
        float t = acc[i][j][c] + bb[j];
        acc[i][j][c] = t > 0.f ? t : 0.f;
      }

  if (MODE == 1){
    float gg_[8], be[8];
    #pragma unroll
    for (int j = 0; j < 8; j++){ gg_[j] = gamma[j*16 + r16]; be[j] = beta[j*16 + r16]; }
    float mn[2][4], rs[2][4];
    #pragma unroll
    for (int i = 0; i < 2; i++)
      #pragma unroll
      for (int c = 0; c < 4; c++){
        float ss = 0.f, qq = 0.f;
        #pragma unroll
        for (int j = 0; j < 8; j++){ float t = acc[i][j][c]; ss += t; qq += t*t; }
        #pragma unroll
        for (int off = 1; off < 16; off <<= 1){
          ss += __shfl_xor(ss, off);
          qq += __shfl_xor(qq, off);
        }
        float m   = ss * (1.f/128.f);
        float var = qq * (1.f/128.f) - m*m;
        mn[i][c] = m;
        rs[i][c] = rsqrtf(var + 1e-5f);
      }
    #pragma unroll
    for (int i = 0; i < 2; i++)
      #pragma unroll
      for (int j = 0; j < 8; j++)
        #pragma unroll
        for (int c = 0; c < 4; c++)
          acc[i][j][c] = (acc[i][j][c] - mn[i][c]) * rs[i][c] * gg_[j] + be[j];
  }

  #pragma unroll
  for (int i = 0; i < 2; i++)
    #pragma unroll
    for (int c = 0; c < 4; c++){
      int grow = rowBase + w*32 + i*16 + g*4 + c;    // C/D: col=lane&15, row=(lane>>4)*4+reg
      if (grow < MM){
        int cch = grow >= NN ? 1 : 0;
        int cn  = grow - cch*NN;
        #pragma unroll
        for (int j = 0; j < 8; j++){
          int col = j*16 + r16;
          if (MODE == 0)      Cu[(size_t)grow*128 + col] = splitpack(acc[i][j][c]);
          else if (MODE == 1) Cu[(size_t)cn*256 + cch*128 + col] = splitpack(acc[i][j][c]);
          else                Cf[(size_t)grow*128 + col] = acc[i][j][c];
        }
      }
    }
}

// ------------------------------------------------------ pooling, 2 phases
__global__ void pool1_kernel(const float* __restrict__ y2, const int* __restrict__ batch,
                             float* __restrict__ sums){
  const int npb = (NN + PB1 - 1)/PB1;   // 49
  int n0 = blockIdx.x * npb;
  if (n0 >= NN) return;
  int n1 = n0 + npb; if (n1 > NN) n1 = NN;
  const int f = threadIdx.x;
  float acc = 0.f;
  int g = batch[n0];
  for (int n = n0; n < n1; n++){
    int bg = batch[n];
    if (bg != g){
      atomicAdd(&sums[(size_t)g*HH + f], acc);
      acc = 0.f; g = bg;
    }
    acc += y2[(size_t)n*HH + f] + y2[(size_t)(NN + n)*HH + f];
  }
  atomicAdd(&sums[(size_t)g*HH + f], acc);
}

__global__ void pool2_kernel(const float* __restrict__ sums, const int* __restrict__ batch,
                             const float* __restrict__ WA, const float* __restrict__ bA,
                             const float* __restrict__ WB, const float* __restrict__ bB,
                             float* __restrict__ out){
  const int g = blockIdx.x, tid = threadIdx.x;
  __shared__ int se[2];
  if (tid < 2){
    int target = g + tid;
    int lo = 0, hi = NN;
    while (lo < hi){ int mid = (lo + hi) >> 1; if (batch[mid] < target) lo = mid + 1; else hi = mid; }
    se[tid] = lo;
  }
  __syncthreads();
  float cnt = (float)(se[1] - se[0]); if (cnt < 1.f) cnt = 1.f;
  __shared__ float ms[HH];
  ms[tid] = sums[(size_t)g*HH + tid] / cnt;
  __syncthreads();
  float t = bA[tid];
  #pragma unroll 8
  for (int k = 0; k < HH; k++) t = fmaf(ms[k], WA[k*HH + tid], t);
  t = t > 0.f ? t : 0.f;
  float v = t * WB[tid];
  #pragma unroll
  for (int off = 32; off >= 1; off >>= 1) v += __shfl_down(v, off);
  __shared__ float r2[2];
  if ((tid & 63) == 0) r2[tid >> 6] = v;
  __syncthreads();
  if (tid == 0) out[g] = r2[0] + r2[1] + bB[0];
}

// ----------------------------------------------------------------- launch
extern "C" void kernel_launch(void* const* d_in, const int* in_sizes, int n_in,
                              void* d_out, int out_size, void* d_ws, size_t ws_size,
                              hipStream_t stream){
  const int*   z     = (const int*)  d_in[0];
  const int*   ei    = (const int*)  d_in[1];
  const int*   batch = (const int*)  d_in[2];
  const float* ztab  = (const float*)d_in[3];
  const float* W1s   = (const float*)d_in[4];
  const float* b1s   = (const float*)d_in[5];
  const float* W2s   = (const float*)d_in[6];
  const float* b2s   = (const float*)d_in[7];
  const float* lng   = (const float*)d_in[8];
  const float* lnb   = (const float*)d_in[9];
  const float* lin0W = (const float*)d_in[10];
  const float* lin0b = (const float*)d_in[11];
  const float* linAW = (const float*)d_in[12];
  const float* linAb = (const float*)d_in[13];
  const float* linBW = (const float*)d_in[14];
  const float* linBb = (const float*)d_in[15];
  float* out = (float*)d_out;

  char* ws = (char*)d_ws;
  size_t off = 0;
  auto alloc = [&](size_t bytes)->char*{
    char* p = ws + off;
    off = (off + bytes + 255) & ~(size_t)255;
    return p;
  };
  u32* xc       = (u32*)alloc((size_t)LL*NN*256*4);  // per-layer LN out, compact
  u32* h_sp     = (u32*)alloc((size_t)MM*HH*4);      // agg out
  u32* t_sp     = (u32*)alloc((size_t)MM*HH*4);      // mid-MLP; aliased as f32 y
  float* y      = (float*)t_sp;
  u16* wt       = (u16*)alloc(294912*2);             // transposed split weights
  float* sums   = (float*)alloc((size_t)GG*HH*4);    // pool partial sums
  int* rowstart = (int*)alloc((size_t)(NN+1)*4);
  int* cursor   = (int*)alloc((size_t)NN*4);
  int* csr      = (int*)alloc((size_t)EE*4);

  const int gemmGrid = (MM + 127)/128;   // 782

  prep_w<<<576, 256, 0, stream>>>(W1s, W2s, lin0W, wt);

  zero_i32<<<(NN + 255)/256, 256, 0, stream>>>(cursor, NN);
  zero_i32<<<(GG*HH)/256, 256, 0, stream>>>((int*)sums, GG*HH);
  deg_kernel<<<EE/256, 256, 0, stream>>>(ei, cursor);
  scan_kernel<<<1, 1024, 0, stream>>>(cursor, rowstart, cursor, NN);
  scatter_kernel<<<EE/256, 256, 0, stream>>>(ei, cursor, csr);

  for (int l = 0; l < LL; l++){
    if (l == 0)
      agg_kernel<true ><<<NN/4, 256, 0, stream>>>(rowstart, csr, z, ztab, nullptr, h_sp);
    else
      agg_kernel<false><<<NN/4, 256, 0, stream>>>(rowstart, csr, z, ztab,
                                                  xc + (size_t)(l-1)*NN*256, h_sp);
    gemm_mfma<128,0><<<gemmGrid, 256, 0, stream>>>(
        h_sp, wt + l*32768, wt + l*32768 + 16384,
        b1s + l*HH, nullptr, nullptr, t_sp, nullptr);
    gemm_mfma<128,1><<<gemmGrid, 256, 0, stream>>>(
        t_sp, wt + 98304 + l*32768, wt + 98304 + l*32768 + 16384,
        b2s + l*HH, lng + l*HH, lnb + l*HH, xc + (size_t)l*NN*256, nullptr);
  }
  gemm_mfma<384,2><<<gemmGrid, 256, 0, stream>>>(
      xc, wt + 196608, wt + 245760,
      lin0b, nullptr, nullptr, nullptr, y);
  pool1_kernel<<<PB1, HH, 0, stream>>>(y, batch, sums);
  pool2_kernel<<<GG, HH, 0, stream>>>(sums, batch, linAW, linAb, linBW, linBb, out);
}

// Round 11
// 591.486 us; speedup vs baseline: 1.9096x; 1.3237x over previous
//
#include <hip/hip_runtime.h>
#include <math.h>

#define NN 50000
#define EE 800000
#define HH 128
#define LL 3
#define GG 128
#define MM (2*NN)
#define PB1 1024   // pool phase-1 blocks

typedef unsigned int u32;
typedef unsigned short u16;
using s16x8 = __attribute__((ext_vector_type(8))) short;
using f32x4 = __attribute__((ext_vector_type(4))) float;

// ---- split-bf16 helpers: value stored as u32 = bf16_hi | (bf16_lo << 16) ----
__device__ __forceinline__ u16 f2bf(float f){
  u32 u = __float_as_uint(f);
  return (u16)((u + 0x7fffu + ((u >> 16) & 1u)) >> 16);   // RNE
}
__device__ __forceinline__ float bf2f(u16 h){ return __uint_as_float(((u32)h) << 16); }
__device__ __forceinline__ u32 splitpack(float v){
  u16 h = f2bf(v);
  float r = v - bf2f(h);
  u16 l = f2bf(r);
  return (u32)h | ((u32)l << 16);
}
__device__ __forceinline__ float unpack2(u32 u){  // hi + lo
  return __uint_as_float(u << 16) + __uint_as_float(u & 0xffff0000u);
}

// ---------------------------------------------------------------- utilities
__global__ void zero_i32(int* p, int n){
  int i = blockIdx.x*blockDim.x + threadIdx.x;
  if (i < n) p[i] = 0;
}

__global__ void deg_kernel(const int* __restrict__ ei, int* __restrict__ deg){
  int e = blockIdx.x*blockDim.x + threadIdx.x;
  if (e < EE) atomicAdd(&deg[ei[EE + e]], 1);
}

// single-block exclusive scan, 4 elements/thread (13 iters over 50k).
// deg may alias cursor: each element read then written by the same thread.
__global__ void scan_kernel(const int* deg, int* rowstart, int* cursor, int n){
  __shared__ int wsum[16], woff[16];
  __shared__ int carry_s;
  const int tid = threadIdx.x, lane = tid & 63, wid = tid >> 6;
  if (tid == 0) carry_s = 0;
  __syncthreads();
  for (int base = 0; base < n; base += 4096){
    int i4 = base + tid*4;
    int4 v = make_int4(0,0,0,0);
    if (i4 + 3 < n) v = *(const int4*)&deg[i4];
    else {
      if (i4+0 < n) v.x = deg[i4+0];
      if (i4+1 < n) v.y = deg[i4+1];
      if (i4+2 < n) v.z = deg[i4+2];
      if (i4+3 < n) v.w = deg[i4+3];
    }
    int s = v.x + v.y + v.z + v.w;
    int incl = s;
    #pragma unroll
    for (int off = 1; off < 64; off <<= 1){
      int t = __shfl_up(incl, off);
      if (lane >= off) incl += t;
    }
    if (lane == 63) wsum[wid] = incl;
    __syncthreads();
    if (tid < 16){
      int wv = wsum[tid];
      int winc = wv;
      #pragma unroll
      for (int off = 1; off < 16; off <<= 1){
        int t = __shfl_up(winc, off);
        if (tid >= off) winc += t;
      }
      woff[tid] = winc - wv;
    }
    __syncthreads();
    int c = carry_s;
    int excl = c + woff[wid] + incl - s;
    if (i4 < n){
      int p = excl;
      rowstart[i4] = p; cursor[i4] = p; p += v.x;
      if (i4+1 < n){ rowstart[i4+1] = p; cursor[i4+1] = p; p += v.y; }
      if (i4+2 < n){ rowstart[i4+2] = p; cursor[i4+2] = p; p += v.z; }
      if (i4+3 < n){ rowstart[i4+3] = p; cursor[i4+3] = p; }
    }
    __syncthreads();
    if (tid == 1023) carry_s = c + woff[15] + incl;
    __syncthreads();
  }
  if (tid == 0) rowstart[n] = carry_s;
}

__global__ void scatter_kernel(const int* __restrict__ ei, int* __restrict__ cursor,
                               int* __restrict__ csr){
  int e = blockIdx.x*blockDim.x + threadIdx.x;
  if (e < EE){
    int d = ei[EE + e];
    int w = atomicAdd(&cursor[d], 1);
    csr[w] = ei[e];
  }
}

// ---------------------------------------------------- weight transpose+split
__global__ void prep_w(const float* __restrict__ W1s, const float* __restrict__ W2s,
                       const float* __restrict__ lin0W, u16* __restrict__ wt){
  int idx = blockIdx.x*256 + threadIdx.x;       // 0..147455
  int srcsel = idx / 49152;
  int r = idx - srcsel*49152;
  int k = r >> 7, c = r & 127;
  const float* src = srcsel==0 ? W1s : (srcsel==1 ? W2s : lin0W);
  float v = src[r];
  u16 h = f2bf(v);
  u16 l = f2bf(v - bf2f(h));
  if (srcsel < 2){
    int ly = k >> 7, kk = k & 127;
    size_t o = (size_t)srcsel*98304 + (size_t)ly*32768 + (size_t)c*128 + kk;
    wt[o] = h; wt[o + 16384] = l;
  } else {
    size_t o = 196608 + (size_t)c*384 + k;
    wt[o] = h; wt[o + 49152] = l;
  }
}

// ------------------------------------------------------------- aggregation
// h[c][n] = x[c][n] + sum_{e: dst==n} x[c][src[e]].
// Non-L0: xin is bf16 [NN][256] (512B/row, both channels); out h split-u32.
// One wave per node: lane reads ushort4 (8B) -> wave covers the 512B row.
template<bool L0>
__global__ void agg_kernel(const int* __restrict__ rowstart, const int* __restrict__ csr,
                           const int* __restrict__ z, const float* __restrict__ ztab,
                           const u16* __restrict__ xin,   // bf16 xc layer [NN][256]
                           u32* __restrict__ hout){       // [2][NN][128] split
  const int lane = threadIdx.x & 63;
  const int n    = blockIdx.x*4 + (threadIdx.x >> 6);
  const int e0 = rowstart[n], e1 = rowstart[n+1];
  if (L0){
    const int f2 = lane*2;
    float2 t0 = *(const float2*)&ztab[f2];
    float2 t1 = *(const float2*)&ztab[HH + f2];
    int c1 = 0, c2 = 0;
    for (int base = e0; base < e1; base += 64){
      if (base + lane < e1){
        int zs = z[csr[base + lane]];
        c1 += (zs == 1); c2 += (zs == 2);
      }
    }
    #pragma unroll
    for (int off = 1; off < 64; off <<= 1){
      c1 += __shfl_xor(c1, off);
      c2 += __shfl_xor(c2, off);
    }
    int zn  = z[n];
    int deg = e1 - e0;
    float w1a = (float)((zn == 1) + c1), w0a = (float)((zn != 1) + deg - c1);
    float w1b = (float)((zn == 2) + c2), w0b = (float)((zn != 2) + deg - c2);
    float2 acc0, acc1;
    acc0.x = w1a*t1.x + w0a*t0.x;  acc0.y = w1a*t1.y + w0a*t0.y;
    acc1.x = w1b*t1.x + w0b*t0.x;  acc1.y = w1b*t1.y + w0b*t0.y;
    *(uint2*)(hout + (size_t)n*HH + f2) =
        make_uint2(splitpack(acc0.x), splitpack(acc0.y));
    *(uint2*)(hout + (size_t)(NN + n)*HH + f2) =
        make_uint2(splitpack(acc1.x), splitpack(acc1.y));
  } else {
    const u16* base = xin + lane*4;          // lane*4 = ch*128 + (lane&31)*4
    ushort4 sv = *(const ushort4*)(base + (size_t)n*256);
    float4 acc;
    acc.x = bf2f(sv.x); acc.y = bf2f(sv.y);
    acc.z = bf2f(sv.z); acc.w = bf2f(sv.w);
    for (int b = e0; b < e1; b += 64){
      int m  = (e1 - b < 64) ? (e1 - b) : 64;
      int sl = (b + lane < e1) ? csr[b + lane] : 0;
      #pragma unroll 4
      for (int j = 0; j < m; ++j){
        int s = __shfl(sl, j);
        ushort4 v = *(const ushort4*)(base + (size_t)s*256);
        acc.x += bf2f(v.x); acc.y += bf2f(v.y);
        acc.z += bf2f(v.z); acc.w += bf2f(v.w);
      }
    }
    uint4 o;
    o.x = splitpack(acc.x); o.y = splitpack(acc.y);
    o.z = splitpack(acc.z); o.w = splitpack(acc.w);
    const int ch = lane >> 5, f = (lane & 31)*4;
    *(uint4*)(hout + ((size_t)ch*NN + n)*HH + f) = o;
  }
}

// ------------------------------------------------------------------- GEMM
// 128x128 tile, 256 threads = 4 waves (wave = 32 rows), mfma_f32_16x16x32_bf16.
// MODE 0: A=[2NN][128] split-u32 (3 MFMA), relu -> C16 t[2NN][128] bf16
// MODE 1: A=t bf16 [2NN][128] (2 MFMA), relu+LN -> C16 xc[n][256] bf16
// MODE 2: A=xc bf16 [3][NN][256] K=384 (2 MFMA), relu -> Cf[2NN][128] f32
template<int K, int MODE>
__global__ __launch_bounds__(256, 4)
void gemm_mfma(const void* __restrict__ Asp,
               const u16* __restrict__ WtHi, const u16* __restrict__ WtLo,
               const float* __restrict__ bias,
               const float* __restrict__ gamma, const float* __restrict__ beta,
               u16* __restrict__ C16, float* __restrict__ Cf){
  constexpr bool ASPLIT = (MODE == 0);
  // LDS (u16): A_hi[0,4096) A_lo[4096,8192) B_hi[8192,12288) B_lo[12288,16384)
  // frag layout: [g(4)][row/col(128)][8 bf16]
  __shared__ u16 lds[16384];
  const int tid  = threadIdx.x;
  const int lane = tid & 63, w = tid >> 6;
  const int r16  = lane & 15, g = lane >> 4;
  const int rowBase = blockIdx.x * 128;

  f32x4 acc[2][8];
  #pragma unroll
  for (int i = 0; i < 2; i++)
    #pragma unroll
    for (int j = 0; j < 8; j++) acc[i][j] = (f32x4){0.f,0.f,0.f,0.f};

  const int sr = tid & 127;       // staging row (A) / col (B)
  const int kq = tid >> 7;        // k-half within 32-chunk
  const int arow = rowBase + sr;
  const bool avalid = arow < MM;
  const int ach = arow >= NN ? 1 : 0;
  const int an  = arow - ach*NN;

  const u16* whi = WtHi + (size_t)sr*K + kq*16;
  const u16* wlo = WtLo + (size_t)sr*K + kq*16;

  for (int kc = 0; kc < K; kc += 32){
    const int k0 = kc + kq*16;
    if (ASPLIT){
      const u32* ap = (const u32*)Asp + (size_t)arow*128 + k0;
      #pragma unroll
      for (int q = 0; q < 4; q++){
        uint4 av = make_uint4(0,0,0,0);
        if (avalid) av = *(const uint4*)(ap + q*4);
        u32 h01 = (av.x & 0xffffu) | (av.y << 16);
        u32 h23 = (av.z & 0xffffu) | (av.w << 16);
        u32 l01 = (av.x >> 16) | (av.y & 0xffff0000u);
        u32 l23 = (av.z >> 16) | (av.w & 0xffff0000u);
        int k = kq*16 + q*4;                       // 0..31 in chunk
        int base = ((k >> 3)*128 + sr)*8 + (k & 7);
        *(uint2*)&lds[base]        = make_uint2(h01, h23);
        *(uint2*)&lds[4096 + base] = make_uint2(l01, l23);
      }
    } else {
      const u16* ap;
      if (MODE == 2)
        ap = (const u16*)Asp + ((size_t)(k0 >> 7))*NN*256 + (size_t)an*256 + ach*128 + (k0 & 127);
      else
        ap = (const u16*)Asp + (size_t)arow*128 + k0;
      #pragma unroll
      for (int hg = 0; hg < 2; hg++){
        uint4 av = make_uint4(0,0,0,0);
        if (avalid) av = *(const uint4*)(ap + hg*8);
        *(uint4*)&lds[((kq*2 + hg)*128 + sr)*8] = av;
      }
    }
    #pragma unroll
    for (int hg = 0; hg < 2; hg++){
      int gsel = kq*2 + hg;
      *(uint4*)&lds[8192  + (gsel*128 + sr)*8] = *(const uint4*)(whi + kc + hg*8);
      *(uint4*)&lds[12288 + (gsel*128 + sr)*8] = *(const uint4*)(wlo + kc + hg*8);
    }
    __syncthreads();
    s16x8 ahi[2], alo[2];
    #pragma unroll
    for (int i = 0; i < 2; i++){
      int idx = (g*128 + w*32 + i*16 + r16)*8;
      ahi[i] = *(const s16x8*)&lds[idx];
      if (ASPLIT) alo[i] = *(const s16x8*)&lds[4096 + idx];
    }
    #pragma unroll
    for (int j = 0; j < 8; j++){
      int bidx = (g*128 + j*16 + r16)*8;
      s16x8 bhi = *(const s16x8*)&lds[8192  + bidx];
      s16x8 blo = *(const s16x8*)&lds[12288 + bidx];
      #pragma unroll
      for (int i = 0; i < 2; i++){
        acc[i][j] = __builtin_amdgcn_mfma_f32_16x16x32_bf16(ahi[i], bhi, acc[i][j], 0, 0, 0);
        acc[i][j] = __builtin_amdgcn_mfma_f32_16x16x32_bf16(ahi[i], blo, acc[i][j], 0, 0, 0);
        if (ASPLIT)
          acc[i][j] = __builtin_amdgcn_mfma_f32_16x16x32_bf16(alo[i], bhi, acc[i][j], 0, 0, 0);
      }
    }
    __syncthreads();
  }

  // ---- epilogue: bias + relu (+ LN) + store ----
  float bb[8];
  #pragma unroll
  for (int j = 0; j < 8; j++) bb[j] = bias[j*16 + r16];
  #pragma unroll
  for (int i = 0; i < 2; i++)
    #pragma unroll
    for (int j = 0; j < 8; j++)
      #pragma unroll
      for (int c = 0; c < 4; c++){
        float t = acc[i][j][c] + bb[j];
        acc[i][j][c] = t > 0.f ? t : 0.f;
      }

  if (MODE == 1){
    float gg_[8], be[8];
    #pragma unroll
    for (int j = 0; j < 8; j++){ gg_[j] = gamma[j*16 + r16]; be[j] = beta[j*16 + r16]; }
    float mn[2][4], rs[2][4];
    #pragma unroll
    for (int i = 0; i < 2; i++)
      #pragma unroll
      for (int c = 0; c < 4; c++){
        float ss = 0.f, qq = 0.f;
        #pragma unroll
        for (int j = 0; j < 8; j++){ float t = acc[i][j][c]; ss += t; qq += t*t; }
        #pragma unroll
        for (int off = 1; off < 16; off <<= 1){
          ss += __shfl_xor(ss, off);
          qq += __shfl_xor(qq, off);
        }
        float m   = ss * (1.f/128.f);
        float var = qq * (1.f/128.f) - m*m;
        mn[i][c] = m;
        rs[i][c] = rsqrtf(var + 1e-5f);
      }
    #pragma unroll
    for (int i = 0; i < 2; i++)
      #pragma unroll
      for (int j = 0; j < 8; j++)
        #pragma unroll
        for (int c = 0; c < 4; c++)
          acc[i][j][c] = (acc[i][j][c] - mn[i][c]) * rs[i][c] * gg_[j] + be[j];
  }

  #pragma unroll
  for (int i = 0; i < 2; i++)
    #pragma unroll
    for (int c = 0; c < 4; c++){
      int grow = rowBase + w*32 + i*16 + g*4 + c;    // C/D: col=lane&15, row=(lane>>4)*4+reg
      if (grow < MM){
        int cch = grow >= NN ? 1 : 0;
        int cn  = grow - cch*NN;
        #pragma unroll
        for (int j = 0; j < 8; j++){
          int col = j*16 + r16;
          if (MODE == 0)      C16[(size_t)grow*128 + col] = f2bf(acc[i][j][c]);
          else if (MODE == 1) C16[(size_t)cn*256 + cch*128 + col] = f2bf(acc[i][j][c]);
          else                Cf [(size_t)grow*128 + col] = acc[i][j][c];
        }
      }
    }
}

// ------------------------------------------------------ pooling, 2 phases
__global__ void pool1_kernel(const float* __restrict__ y2, const int* __restrict__ batch,
                             float* __restrict__ sums){
  const int npb = (NN + PB1 - 1)/PB1;   // 49
  int n0 = blockIdx.x * npb;
  if (n0 >= NN) return;
  int n1 = n0 + npb; if (n1 > NN) n1 = NN;
  const int f = threadIdx.x;
  float acc = 0.f;
  int g = batch[n0];
  for (int n = n0; n < n1; n++){
    int bg = batch[n];
    if (bg != g){
      atomicAdd(&sums[(size_t)g*HH + f], acc);
      acc = 0.f; g = bg;
    }
    acc += y2[(size_t)n*HH + f] + y2[(size_t)(NN + n)*HH + f];
  }
  atomicAdd(&sums[(size_t)g*HH + f], acc);
}

__global__ void pool2_kernel(const float* __restrict__ sums, const int* __restrict__ batch,
                             const float* __restrict__ WA, const float* __restrict__ bA,
                             const float* __restrict__ WB, const float* __restrict__ bB,
                             float* __restrict__ out){
  const int g = blockIdx.x, tid = threadIdx.x;
  __shared__ int se[2];
  if (tid < 2){
    int target = g + tid;
    int lo = 0, hi = NN;
    while (lo < hi){ int mid = (lo + hi) >> 1; if (batch[mid] < target) lo = mid + 1; else hi = mid; }
    se[tid] = lo;
  }
  __syncthreads();
  float cnt = (float)(se[1] - se[0]); if (cnt < 1.f) cnt = 1.f;
  __shared__ float ms[HH];
  ms[tid] = sums[(size_t)g*HH + tid] / cnt;
  __syncthreads();
  float t = bA[tid];
  #pragma unroll 8
  for (int k = 0; k < HH; k++) t = fmaf(ms[k], WA[k*HH + tid], t);
  t = t > 0.f ? t : 0.f;
  float v = t * WB[tid];
  #pragma unroll
  for (int off = 32; off >= 1; off >>= 1) v += __shfl_down(v, off);
  __shared__ float r2[2];
  if ((tid & 63) == 0) r2[tid >> 6] = v;
  __syncthreads();
  if (tid == 0) out[g] = r2[0] + r2[1] + bB[0];
}

// ----------------------------------------------------------------- launch
extern "C" void kernel_launch(void* const* d_in, const int* in_sizes, int n_in,
                              void* d_out, int out_size, void* d_ws, size_t ws_size,
                              hipStream_t stream){
  const int*   z     = (const int*)  d_in[0];
  const int*   ei    = (const int*)  d_in[1];
  const int*   batch = (const int*)  d_in[2];
  const float* ztab  = (const float*)d_in[3];
  const float* W1s   = (const float*)d_in[4];
  const float* b1s   = (const float*)d_in[5];
  const float* W2s   = (const float*)d_in[6];
  const float* b2s   = (const float*)d_in[7];
  const float* lng   = (const float*)d_in[8];
  const float* lnb   = (const float*)d_in[9];
  const float* lin0W = (const float*)d_in[10];
  const float* lin0b = (const float*)d_in[11];
  const float* linAW = (const float*)d_in[12];
  const float* linAb = (const float*)d_in[13];
  const float* linBW = (const float*)d_in[14];
  const float* linBb = (const float*)d_in[15];
  float* out = (float*)d_out;

  char* ws = (char*)d_ws;
  size_t off = 0;
  auto alloc = [&](size_t bytes)->char*{
    char* p = ws + off;
    off = (off + bytes + 255) & ~(size_t)255;
    return p;
  };
  u16* xc       = (u16*)alloc((size_t)LL*NN*256*2);  // per-layer LN out, bf16
  u32* h_sp     = (u32*)alloc((size_t)MM*HH*4);      // agg out (split); y aliases
  float* y      = (float*)h_sp;                      // lin0 out (h dead by then)
  u16* t16      = (u16*)alloc((size_t)MM*HH*2);      // mid-MLP, bf16
  u16* wt       = (u16*)alloc(294912*2);             // transposed split weights
  float* sums   = (float*)alloc((size_t)GG*HH*4);    // pool partial sums
  int* rowstart = (int*)alloc((size_t)(NN+1)*4);
  int* cursor   = (int*)alloc((size_t)NN*4);
  int* csr      = (int*)alloc((size_t)EE*4);

  const int gemmGrid = (MM + 127)/128;   // 782

  prep_w<<<576, 256, 0, stream>>>(W1s, W2s, lin0W, wt);

  zero_i32<<<(NN + 255)/256, 256, 0, stream>>>(cursor, NN);
  zero_i32<<<(GG*HH)/256, 256, 0, stream>>>((int*)sums, GG*HH);
  deg_kernel<<<EE/256, 256, 0, stream>>>(ei, cursor);
  scan_kernel<<<1, 1024, 0, stream>>>(cursor, rowstart, cursor, NN);
  scatter_kernel<<<EE/256, 256, 0, stream>>>(ei, cursor, csr);

  for (int l = 0; l < LL; l++){
    if (l == 0)
      agg_kernel<true ><<<NN/4, 256, 0, stream>>>(rowstart, csr, z, ztab, nullptr, h_sp);
    else
      agg_kernel<false><<<NN/4, 256, 0, stream>>>(rowstart, csr, z, ztab,
                                                  xc + (size_t)(l-1)*NN*256, h_sp);
    gemm_mfma<128,0><<<gemmGrid, 256, 0, stream>>>(
        h_sp, wt + l*32768, wt + l*32768 + 16384,
        b1s + l*HH, nullptr, nullptr, t16, nullptr);
    gemm_mfma<128,1><<<gemmGrid, 256, 0, stream>>>(
        t16, wt + 98304 + l*32768, wt + 98304 + l*32768 + 16384,
        b2s + l*HH, lng + l*HH, lnb + l*HH, xc + (size_t)l*NN*256, nullptr);
  }
  gemm_mfma<384,2><<<gemmGrid, 256, 0, stream>>>(
      xc, wt + 196608, wt + 245760,
      lin0b, nullptr, nullptr, nullptr, y);
  pool1_kernel<<<PB1, HH, 0, stream>>>(y, batch, sums);
  pool2_kernel<<<GG, HH, 0, stream>>>(sums, batch, linAW, linAb, linBW, linBb, out);
}

// Round 13
// 561.190 us; speedup vs baseline: 2.0127x; 1.0540x over previous
//
#include <hip/hip_runtime.h>
#include <math.h>

#define NN 50000
#define EE 800000
#define HH 128
#define LL 3
#define GG 128
#define MM (2*NN)
#define PB1 1024   // pool phase-1 blocks

typedef unsigned int u32;
typedef unsigned short u16;
using s16x8 = __attribute__((ext_vector_type(8))) short;
using f32x4 = __attribute__((ext_vector_type(4))) float;

// ---- split-bf16 helpers: value stored as u32 = bf16_hi | (bf16_lo << 16) ----
__device__ __forceinline__ u16 f2bf(float f){
  u32 u = __float_as_uint(f);
  return (u16)((u + 0x7fffu + ((u >> 16) & 1u)) >> 16);   // RNE
}
__device__ __forceinline__ float bf2f(u16 h){ return __uint_as_float(((u32)h) << 16); }
__device__ __forceinline__ u32 splitpack(float v){
  u16 h = f2bf(v);
  float r = v - bf2f(h);
  u16 l = f2bf(r);
  return (u32)h | ((u32)l << 16);
}

// ---------------------------------------------------------------- utilities
__global__ void zero_i32(int* p, int n){
  int i = blockIdx.x*blockDim.x + threadIdx.x;
  if (i < n) p[i] = 0;
}

__global__ void deg_kernel(const int* __restrict__ ei, int* __restrict__ deg){
  int e = blockIdx.x*blockDim.x + threadIdx.x;
  if (e < EE) atomicAdd(&deg[ei[EE + e]], 1);
}

// single-block exclusive scan, 4 elements/thread.
__global__ void scan_kernel(const int* deg, int* rowstart, int* cursor, int n){
  __shared__ int wsum[16], woff[16];
  __shared__ int carry_s;
  const int tid = threadIdx.x, lane = tid & 63, wid = tid >> 6;
  if (tid == 0) carry_s = 0;
  __syncthreads();
  for (int base = 0; base < n; base += 4096){
    int i4 = base + tid*4;
    int4 v = make_int4(0,0,0,0);
    if (i4 + 3 < n) v = *(const int4*)&deg[i4];
    else {
      if (i4+0 < n) v.x = deg[i4+0];
      if (i4+1 < n) v.y = deg[i4+1];
      if (i4+2 < n) v.z = deg[i4+2];
      if (i4+3 < n) v.w = deg[i4+3];
    }
    int s = v.x + v.y + v.z + v.w;
    int incl = s;
    #pragma unroll
    for (int off = 1; off < 64; off <<= 1){
      int t = __shfl_up(incl, off);
      if (lane >= off) incl += t;
    }
    if (lane == 63) wsum[wid] = incl;
    __syncthreads();
    if (tid < 16){
      int wv = wsum[tid];
      int winc = wv;
      #pragma unroll
      for (int off = 1; off < 16; off <<= 1){
        int t = __shfl_up(winc, off);
        if (tid >= off) winc += t;
      }
      woff[tid] = winc - wv;
    }
    __syncthreads();
    int c = carry_s;
    int excl = c + woff[wid] + incl - s;
    if (i4 < n){
      int p = excl;
      rowstart[i4] = p; cursor[i4] = p; p += v.x;
      if (i4+1 < n){ rowstart[i4+1] = p; cursor[i4+1] = p; p += v.y; }
      if (i4+2 < n){ rowstart[i4+2] = p; cursor[i4+2] = p; p += v.z; }
      if (i4+3 < n){ rowstart[i4+3] = p; cursor[i4+3] = p; }
    }
    __syncthreads();
    if (tid == 1023) carry_s = c + woff[15] + incl;
    __syncthreads();
  }
  if (tid == 0) rowstart[n] = carry_s;
}

__global__ void scatter_kernel(const int* __restrict__ ei, int* __restrict__ cursor,
                               int* __restrict__ csr){
  int e = blockIdx.x*blockDim.x + threadIdx.x;
  if (e < EE){
    int d = ei[EE + e];
    int w = atomicAdd(&cursor[d], 1);
    csr[w] = ei[e];
  }
}

// ---------------------------------------------------- weight transpose+split
__global__ void prep_w(const float* __restrict__ W1s, const float* __restrict__ W2s,
                       const float* __restrict__ lin0W, u16* __restrict__ wt){
  int idx = blockIdx.x*256 + threadIdx.x;       // 0..147455
  int srcsel = idx / 49152;
  int r = idx - srcsel*49152;
  int k = r >> 7, c = r & 127;
  const float* src = srcsel==0 ? W1s : (srcsel==1 ? W2s : lin0W);
  float v = src[r];
  u16 h = f2bf(v);
  u16 l = f2bf(v - bf2f(h));
  if (srcsel < 2){
    int ly = k >> 7, kk = k & 127;
    size_t o = (size_t)srcsel*98304 + (size_t)ly*32768 + (size_t)c*128 + kk;
    wt[o] = h; wt[o + 16384] = l;
  } else {
    size_t o = 196608 + (size_t)c*384 + k;
    wt[o] = h; wt[o + 49152] = l;
  }
}

// ------------------------------------------------------------- aggregation
// h[c][n] = x[c][n] + sum_{e: dst==n} x[c][src[e]].
// Non-L0: xin bf16 [NN][256] (512B/row); out h split-u32. One wave per node.
template<bool L0>
__global__ void agg_kernel(const int* __restrict__ rowstart, const int* __restrict__ csr,
                           const int* __restrict__ z, const float* __restrict__ ztab,
                           const u16* __restrict__ xin,
                           u32* __restrict__ hout){       // [2][NN][128] split
  const int lane = threadIdx.x & 63;
  const int n    = blockIdx.x*4 + (threadIdx.x >> 6);
  const int e0 = rowstart[n], e1 = rowstart[n+1];
  if (L0){
    const int f2 = lane*2;
    float2 t0 = *(const float2*)&ztab[f2];
    float2 t1 = *(const float2*)&ztab[HH + f2];
    int c1 = 0, c2 = 0;
    for (int base = e0; base < e1; base += 64){
      if (base + lane < e1){
        int zs = z[csr[base + lane]];
        c1 += (zs == 1); c2 += (zs == 2);
      }
    }
    #pragma unroll
    for (int off = 1; off < 64; off <<= 1){
      c1 += __shfl_xor(c1, off);
      c2 += __shfl_xor(c2, off);
    }
    int zn  = z[n];
    int deg = e1 - e0;
    float w1a = (float)((zn == 1) + c1), w0a = (float)((zn != 1) + deg - c1);
    float w1b = (float)((zn == 2) + c2), w0b = (float)((zn != 2) + deg - c2);
    float2 acc0, acc1;
    acc0.x = w1a*t1.x + w0a*t0.x;  acc0.y = w1a*t1.y + w0a*t0.y;
    acc1.x = w1b*t1.x + w0b*t0.x;  acc1.y = w1b*t1.y + w0b*t0.y;
    *(uint2*)(hout + (size_t)n*HH + f2) =
        make_uint2(splitpack(acc0.x), splitpack(acc0.y));
    *(uint2*)(hout + (size_t)(NN + n)*HH + f2) =
        make_uint2(splitpack(acc1.x), splitpack(acc1.y));
  } else {
    const u16* base = xin + lane*4;          // lane*4 = ch*128 + (lane&31)*4
    ushort4 sv = *(const ushort4*)(base + (size_t)n*256);
    float4 acc;
    acc.x = bf2f(sv.x); acc.y = bf2f(sv.y);
    acc.z = bf2f(sv.z); acc.w = bf2f(sv.w);
    for (int b = e0; b < e1; b += 64){
      int m  = (e1 - b < 64) ? (e1 - b) : 64;
      int sl = (b + lane < e1) ? csr[b + lane] : 0;
      #pragma unroll 4
      for (int j = 0; j < m; ++j){
        int s = __shfl(sl, j);
        ushort4 v = *(const ushort4*)(base + (size_t)s*256);
        acc.x += bf2f(v.x); acc.y += bf2f(v.y);
        acc.z += bf2f(v.z); acc.w += bf2f(v.w);
      }
    }
    uint4 o;
    o.x = splitpack(acc.x); o.y = splitpack(acc.y);
    o.z = splitpack(acc.z); o.w = splitpack(acc.w);
    const int ch = lane >> 5, f = (lane & 31)*4;
    *(uint4*)(hout + ((size_t)ch*NN + n)*HH + f) = o;
  }
}

// ---------------------------------------------------- fused per-layer MLP
// Phase 1: t = relu(h @ W1 + b1)   (h split-u32, 3-MFMA split path)
// t tile (128x128 bf16) kept in LDS in A-fragment layout (col -> k of phase 2)
// Phase 2: xc = LN(relu(t @ W2 + b2)) (bf16 A, 2-MFMA path)
// LDS: [0,16384) staging A_hi/A_lo/B_hi/B_lo (phase1) then t-tile;
//      [16384,24576) W2 staging hi/lo. 48KB -> 3 blocks/CU.
__global__ __launch_bounds__(256, 3)
void mlp_fused(const u32* __restrict__ hsp,
               const u16* __restrict__ W1hi, const u16* __restrict__ W1lo,
               const float* __restrict__ b1,
               const u16* __restrict__ W2hi, const u16* __restrict__ W2lo,
               const float* __restrict__ b2,
               const float* __restrict__ gamma, const float* __restrict__ beta,
               u16* __restrict__ xcout){
  __shared__ u16 lds[24576];
  const int tid  = threadIdx.x;
  const int lane = tid & 63, w = tid >> 6;
  const int r16  = lane & 15, g = lane >> 4;
  const int rowBase = blockIdx.x * 128;

  const int sr = tid & 127;       // staging row (A) / col (B)
  const int kq = tid >> 7;        // k-half within 32-chunk
  const int arow = rowBase + sr;
  const bool avalid = arow < MM;

  f32x4 acc[2][8];
  #pragma unroll
  for (int i = 0; i < 2; i++)
    #pragma unroll
    for (int j = 0; j < 8; j++) acc[i][j] = (f32x4){0.f,0.f,0.f,0.f};

  const u16* whi1 = W1hi + (size_t)sr*128 + kq*16;
  const u16* wlo1 = W1lo + (size_t)sr*128 + kq*16;

  // ---------------- phase 1: h @ W1 ----------------
  for (int kc = 0; kc < 128; kc += 32){
    const int k0 = kc + kq*16;
    const u32* ap = hsp + (size_t)arow*128 + k0;
    #pragma unroll
    for (int q = 0; q < 4; q++){
      uint4 av = make_uint4(0,0,0,0);
      if (avalid) av = *(const uint4*)(ap + q*4);
      u32 h01 = (av.x & 0xffffu) | (av.y << 16);
      u32 h23 = (av.z & 0xffffu) | (av.w << 16);
      u32 l01 = (av.x >> 16) | (av.y & 0xffff0000u);
      u32 l23 = (av.z >> 16) | (av.w & 0xffff0000u);
      int k = kq*16 + q*4;
      int base = ((k >> 3)*128 + sr)*8 + (k & 7);
      *(uint2*)&lds[base]        = make_uint2(h01, h23);
      *(uint2*)&lds[4096 + base] = make_uint2(l01, l23);
    }
    #pragma unroll
    for (int hg = 0; hg < 2; hg++){
      int gsel = kq*2 + hg;
      *(uint4*)&lds[8192  + (gsel*128 + sr)*8] = *(const uint4*)(whi1 + kc + hg*8);
      *(uint4*)&lds[12288 + (gsel*128 + sr)*8] = *(const uint4*)(wlo1 + kc + hg*8);
    }
    __syncthreads();
    s16x8 ahi[2], alo[2];
    #pragma unroll
    for (int i = 0; i < 2; i++){
      int idx = (g*128 + w*32 + i*16 + r16)*8;
      ahi[i] = *(const s16x8*)&lds[idx];
      alo[i] = *(const s16x8*)&lds[4096 + idx];
    }
    #pragma unroll
    for (int j = 0; j < 8; j++){
      int bidx = (g*128 + j*16 + r16)*8;
      s16x8 bhi = *(const s16x8*)&lds[8192  + bidx];
      s16x8 blo = *(const s16x8*)&lds[12288 + bidx];
      #pragma unroll
      for (int i = 0; i < 2; i++){
        acc[i][j] = __builtin_amdgcn_mfma_f32_16x16x32_bf16(ahi[i], bhi, acc[i][j], 0, 0, 0);
        acc[i][j] = __builtin_amdgcn_mfma_f32_16x16x32_bf16(ahi[i], blo, acc[i][j], 0, 0, 0);
        acc[i][j] = __builtin_amdgcn_mfma_f32_16x16x32_bf16(alo[i], bhi, acc[i][j], 0, 0, 0);
      }
    }
    __syncthreads();
  }

  // bias + relu, write t tile into LDS [0,16384) in phase-2 A-frag layout:
  // t[k=col][row] at ((col>>3)*128 + row)*8 + (col&7)
  {
    float bb[8];
    #pragma unroll
    for (int j = 0; j < 8; j++) bb[j] = b1[j*16 + r16];
    #pragma unroll
    for (int i = 0; i < 2; i++)
      #pragma unroll
      for (int c = 0; c < 4; c++){
        int row = w*32 + i*16 + g*4 + c;     // C/D: col=lane&15, row=(lane>>4)*4+reg
        #pragma unroll
        for (int j = 0; j < 8; j++){
          int col = j*16 + r16;
          float t = acc[i][j][c] + bb[j];
          t = t > 0.f ? t : 0.f;
          lds[((col >> 3)*128 + row)*8 + (col & 7)] = f2bf(t);
        }
      }
  }
  __syncthreads();

  // ---------------- phase 2: t @ W2 ----------------
  f32x4 acc2[2][8];
  #pragma unroll
  for (int i = 0; i < 2; i++)
    #pragma unroll
    for (int j = 0; j < 8; j++) acc2[i][j] = (f32x4){0.f,0.f,0.f,0.f};

  const u16* whi2 = W2hi + (size_t)sr*128 + kq*16;
  const u16* wlo2 = W2lo + (size_t)sr*128 + kq*16;

  for (int kc = 0; kc < 128; kc += 32){
    #pragma unroll
    for (int hg = 0; hg < 2; hg++){
      int gsel = kq*2 + hg;
      *(uint4*)&lds[16384 + (gsel*128 + sr)*8] = *(const uint4*)(whi2 + kc + hg*8);
      *(uint4*)&lds[20480 + (gsel*128 + sr)*8] = *(const uint4*)(wlo2 + kc + hg*8);
    }
    __syncthreads();
    s16x8 a2[2];
    #pragma unroll
    for (int i = 0; i < 2; i++){
      int oct = (kc >> 3) + g;
      a2[i] = *(const s16x8*)&lds[(oct*128 + w*32 + i*16 + r16)*8];
    }
    #pragma unroll
    for (int j = 0; j < 8; j++){
      int bidx = (g*128 + j*16 + r16)*8;
      s16x8 bhi = *(const s16x8*)&lds[16384 + bidx];
      s16x8 blo = *(const s16x8*)&lds[20480 + bidx];
      #pragma unroll
      for (int i = 0; i < 2; i++){
        acc2[i][j] = __builtin_amdgcn_mfma_f32_16x16x32_bf16(a2[i], bhi, acc2[i][j], 0, 0, 0);
        acc2[i][j] = __builtin_amdgcn_mfma_f32_16x16x32_bf16(a2[i], blo, acc2[i][j], 0, 0, 0);
      }
    }
    __syncthreads();
  }

  // ---- epilogue: bias + relu + LN + store bf16 to xc [n][256] ----
  float bb[8], gg_[8], be[8];
  #pragma unroll
  for (int j = 0; j < 8; j++){
    bb[j]  = b2[j*16 + r16];
    gg_[j] = gamma[j*16 + r16];
    be[j]  = beta[j*16 + r16];
  }
  #pragma unroll
  for (int i = 0; i < 2; i++)
    #pragma unroll
    for (int j = 0; j < 8; j++)
      #pragma unroll
      for (int c = 0; c < 4; c++){
        float t = acc2[i][j][c] + bb[j];
        acc2[i][j][c] = t > 0.f ? t : 0.f;
      }
  float mn[2][4], rs[2][4];
  #pragma unroll
  for (int i = 0; i < 2; i++)
    #pragma unroll
    for (int c = 0; c < 4; c++){
      float ss = 0.f, qq = 0.f;
      #pragma unroll
      for (int j = 0; j < 8; j++){ float t = acc2[i][j][c]; ss += t; qq += t*t; }
      #pragma unroll
      for (int off = 1; off < 16; off <<= 1){
        ss += __shfl_xor(ss, off);
        qq += __shfl_xor(qq, off);
      }
      float m   = ss * (1.f/128.f);
      float var = qq * (1.f/128.f) - m*m;
      mn[i][c] = m;
      rs[i][c] = rsqrtf(var + 1e-5f);
    }
  #pragma unroll
  for (int i = 0; i < 2; i++)
    #pragma unroll
    for (int c = 0; c < 4; c++){
      int grow = rowBase + w*32 + i*16 + g*4 + c;
      if (grow < MM){
        int cch = grow >= NN ? 1 : 0;
        int cn  = grow - cch*NN;
        #pragma unroll
        for (int j = 0; j < 8; j++){
          int col = j*16 + r16;
          float v = (acc2[i][j][c] - mn[i][c]) * rs[i][c] * gg_[j] + be[j];
          xcout[(size_t)cn*256 + cch*128 + col] = f2bf(v);
        }
      }
    }
}

// ------------------------------------------------------------- lin0 GEMM
// A = xc triple [3][NN][256] bf16 (K=384), epilogue relu -> y bf16 [2NN][128]
__global__ __launch_bounds__(256, 4)
void gemm_lin0(const u16* __restrict__ Axc,
               const u16* __restrict__ WtHi, const u16* __restrict__ WtLo,
               const float* __restrict__ bias, u16* __restrict__ Y16){
  __shared__ u16 lds[16384];
  const int tid  = threadIdx.x;
  const int lane = tid & 63, w = tid >> 6;
  const int r16  = lane & 15, g = lane >> 4;
  const int rowBase = blockIdx.x * 128;

  f32x4 acc[2][8];
  #pragma unroll
  for (int i = 0; i < 2; i++)
    #pragma unroll
    for (int j = 0; j < 8; j++) acc[i][j] = (f32x4){0.f,0.f,0.f,0.f};

  const int sr = tid & 127;
  const int kq = tid >> 7;
  const int arow = rowBase + sr;
  const bool avalid = arow < MM;
  const int ach = arow >= NN ? 1 : 0;
  const int an  = arow - ach*NN;

  const u16* whi = WtHi + (size_t)sr*384 + kq*16;
  const u16* wlo = WtLo + (size_t)sr*384 + kq*16;

  for (int kc = 0; kc < 384; kc += 32){
    const int k0 = kc + kq*16;
    const u16* ap = Axc + ((size_t)(k0 >> 7))*NN*256 + (size_t)an*256 + ach*128 + (k0 & 127);
    #pragma unroll
    for (int hg = 0; hg < 2; hg++){
      uint4 av = make_uint4(0,0,0,0);
      if (avalid) av = *(const uint4*)(ap + hg*8);
      *(uint4*)&lds[((kq*2 + hg)*128 + sr)*8] = av;
    }
    #pragma unroll
    for (int hg = 0; hg < 2; hg++){
      int gsel = kq*2 + hg;
      *(uint4*)&lds[8192  + (gsel*128 + sr)*8] = *(const uint4*)(whi + kc + hg*8);
      *(uint4*)&lds[12288 + (gsel*128 + sr)*8] = *(const uint4*)(wlo + kc + hg*8);
    }
    __syncthreads();
    s16x8 ahi[2];
    #pragma unroll
    for (int i = 0; i < 2; i++)
      ahi[i] = *(const s16x8*)&lds[(g*128 + w*32 + i*16 + r16)*8];
    #pragma unroll
    for (int j = 0; j < 8; j++){
      int bidx = (g*128 + j*16 + r16)*8;
      s16x8 bhi = *(const s16x8*)&lds[8192  + bidx];
      s16x8 blo = *(const s16x8*)&lds[12288 + bidx];
      #pragma unroll
      for (int i = 0; i < 2; i++){
        acc[i][j] = __builtin_amdgcn_mfma_f32_16x16x32_bf16(ahi[i], bhi, acc[i][j], 0, 0, 0);
        acc[i][j] = __builtin_amdgcn_mfma_f32_16x16x32_bf16(ahi[i], blo, acc[i][j], 0, 0, 0);
      }
    }
    __syncthreads();
  }

  float bb[8];
  #pragma unroll
  for (int j = 0; j < 8; j++) bb[j] = bias[j*16 + r16];
  #pragma unroll
  for (int i = 0; i < 2; i++)
    #pragma unroll
    for (int c = 0; c < 4; c++){
      int grow = rowBase + w*32 + i*16 + g*4 + c;
      if (grow < MM){
        #pragma unroll
        for (int j = 0; j < 8; j++){
          float t = acc[i][j][c] + bb[j];
          t = t > 0.f ? t : 0.f;
          Y16[(size_t)grow*128 + j*16 + r16] = f2bf(t);
        }
      }
    }
}

// ------------------------------------------------------ pooling, 2 phases
__global__ void pool1_kernel(const u16* __restrict__ y16, const int* __restrict__ batch,
                             float* __restrict__ sums){
  const int npb = (NN + PB1 - 1)/PB1;   // 49
  int n0 = blockIdx.x * npb;
  if (n0 >= NN) return;
  int n1 = n0 + npb; if (n1 > NN) n1 = NN;
  const int f = threadIdx.x;
  float acc = 0.f;
  int g = batch[n0];
  for (int n = n0; n < n1; n++){
    int bg = batch[n];
    if (bg != g){
      atomicAdd(&sums[(size_t)g*HH + f], acc);
      acc = 0.f; g = bg;
    }
    acc += bf2f(y16[(size_t)n*HH + f]) + bf2f(y16[(size_t)(NN + n)*HH + f]);
  }
  atomicAdd(&sums[(size_t)g*HH + f], acc);
}

__global__ void pool2_kernel(const float* __restrict__ sums, const int* __restrict__ batch,
                             const float* __restrict__ WA, const float* __restrict__ bA,
                             const float* __restrict__ WB, const float* __restrict__ bB,
                             float* __restrict__ out){
  const int g = blockIdx.x, tid = threadIdx.x;
  __shared__ int se[2];
  if (tid < 2){
    int target = g + tid;
    int lo = 0, hi = NN;
    while (lo < hi){ int mid = (lo + hi) >> 1; if (batch[mid] < target) lo = mid + 1; else hi = mid; }
    se[tid] = lo;
  }
  __syncthreads();
  float cnt = (float)(se[1] - se[0]); if (cnt < 1.f) cnt = 1.f;
  __shared__ float ms[HH];
  ms[tid] = sums[(size_t)g*HH + tid] / cnt;
  __syncthreads();
  float t = bA[tid];
  #pragma unroll 8
  for (int k = 0; k < HH; k++) t = fmaf(ms[k], WA[k*HH + tid], t);
  t = t > 0.f ? t : 0.f;
  float v = t * WB[tid];
  #pragma unroll
  for (int off = 32; off >= 1; off >>= 1) v += __shfl_down(v, off);
  __shared__ float r2[2];
  if ((tid & 63) == 0) r2[tid >> 6] = v;
  __syncthreads();
  if (tid == 0) out[g] = r2[0] + r2[1] + bB[0];
}

// ----------------------------------------------------------------- launch
extern "C" void kernel_launch(void* const* d_in, const int* in_sizes, int n_in,
                              void* d_out, int out_size, void* d_ws, size_t ws_size,
                              hipStream_t stream){
  const int*   z     = (const int*)  d_in[0];
  const int*   ei    = (const int*)  d_in[1];
  const int*   batch = (const int*)  d_in[2];
  const float* ztab  = (const float*)d_in[3];
  const float* W1s   = (const float*)d_in[4];
  const float* b1s   = (const float*)d_in[5];
  const float* W2s   = (const float*)d_in[6];
  const float* b2s   = (const float*)d_in[7];
  const float* lng   = (const float*)d_in[8];
  const float* lnb   = (const float*)d_in[9];
  const float* lin0W = (const float*)d_in[10];
  const float* lin0b = (const float*)d_in[11];
  const float* linAW = (const float*)d_in[12];
  const float* linAb = (const float*)d_in[13];
  const float* linBW = (const float*)d_in[14];
  const float* linBb = (const float*)d_in[15];
  float* out = (float*)d_out;

  char* ws = (char*)d_ws;
  size_t off = 0;
  auto alloc = [&](size_t bytes)->char*{
    char* p = ws + off;
    off = (off + bytes + 255) & ~(size_t)255;
    return p;
  };
  u16* xc       = (u16*)alloc((size_t)LL*NN*256*2);  // per-layer LN out, bf16
  u32* h_sp     = (u32*)alloc((size_t)MM*HH*4);      // agg out (split); y16 aliases
  u16* y16      = (u16*)h_sp;                        // lin0 out bf16 (h dead by then)
  u16* wt       = (u16*)alloc(294912*2);             // transposed split weights
  float* sums   = (float*)alloc((size_t)GG*HH*4);    // pool partial sums
  int* rowstart = (int*)alloc((size_t)(NN+1)*4);
  int* cursor   = (int*)alloc((size_t)NN*4);
  int* csr      = (int*)alloc((size_t)EE*4);

  const int gemmGrid = (MM + 127)/128;   // 782

  prep_w<<<576, 256, 0, stream>>>(W1s, W2s, lin0W, wt);

  zero_i32<<<(NN + 255)/256, 256, 0, stream>>>(cursor, NN);
  zero_i32<<<(GG*HH)/256, 256, 0, stream>>>((int*)sums, GG*HH);
  deg_kernel<<<EE/256, 256, 0, stream>>>(ei, cursor);
  scan_kernel<<<1, 1024, 0, stream>>>(cursor, rowstart, cursor, NN);
  scatter_kernel<<<EE/256, 256, 0, stream>>>(ei, cursor, csr);

  for (int l = 0; l < LL; l++){
    if (l == 0)
      agg_kernel<true ><<<NN/4, 256, 0, stream>>>(rowstart, csr, z, ztab, nullptr, h_sp);
    else
      agg_kernel<false><<<NN/4, 256, 0, stream>>>(rowstart, csr, z, ztab,
                                                  xc + (size_t)(l-1)*NN*256, h_sp);
    mlp_fused<<<gemmGrid, 256, 0, stream>>>(
        h_sp,
        wt + l*32768, wt + l*32768 + 16384, b1s + l*HH,
        wt + 98304 + l*32768, wt + 98304 + l*32768 + 16384, b2s + l*HH,
        lng + l*HH, lnb + l*HH,
        xc + (size_t)l*NN*256);
  }
  gemm_lin0<<<gemmGrid, 256, 0, stream>>>(xc, wt + 196608, wt + 245760, lin0b, y16);
  pool1_kernel<<<PB1, HH, 0, stream>>>(y16, batch, sums);
  pool2_kernel<<<GG, HH, 0, stream>>>(sums, batch, linAW, linAb, linBW, linBb, out);
}